// Round 12
// baseline (130.124 us; speedup 1.0000x reference)
//
#include <hip/hip_runtime.h>

#define E 1024
#define NSEQ 2048
#define HEADS 16
#define HD 64

typedef unsigned short u16;
typedef short short8 __attribute__((ext_vector_type(8)));
typedef float f32x4 __attribute__((ext_vector_type(4)));
typedef u16 u16x4 __attribute__((ext_vector_type(4)));

template<bool B> struct BC { static constexpr bool v = B; };

#define GLOAD_LDS16(gp, lp)                                        \
    __builtin_amdgcn_global_load_lds(                              \
        (const __attribute__((address_space(1))) void*)(gp),       \
        (__attribute__((address_space(3))) void*)(lp), 16, 0, 0)

__device__ __forceinline__ u16 f2bf(float f) {
    union { float f; unsigned u; } v; v.f = f;
    unsigned r = v.u + 0x7fffu + ((v.u >> 16) & 1u);
    return (u16)(r >> 16);
}

__device__ __forceinline__ unsigned cvt_pk_bf16(float lo, float hi) {
    unsigned r;
    asm("v_cvt_pk_bf16_f32 %0, %1, %2" : "=v"(r) : "v"(lo), "v"(hi));
    return r;
}

__device__ __forceinline__ f32x4 mfma16(short8 a, short8 b, f32x4 c) {
    return __builtin_amdgcn_mfma_f32_16x16x32_bf16(a, b, c, 0, 0, 0);
}

// ---------------- fused: weight f32->bf16 convert + LayerNorm ----------------
__global__ __launch_bounds__(256) void prep_k(
    const float* __restrict__ Wq, const float* __restrict__ Wk,
    const float* __restrict__ Wv, const float* __restrict__ Wo,
    const float* __restrict__ X, const float* __restrict__ w,
    const float* __restrict__ bb, u16* __restrict__ Wbf, u16* __restrict__ xn)
{
    if (blockIdx.x < 4096) {
        const unsigned i = (blockIdx.x * 256u + threadIdx.x) * 4u;
        const unsigned m = i >> 20;
        const float* src = (m == 0) ? Wq : (m == 1) ? Wk : (m == 2) ? Wv : Wo;
        const float4 v = *(const float4*)(src + (i & 0xFFFFFu));
        *(uint2*)(Wbf + i) = make_uint2(
            ((unsigned)f2bf(v.x)) | (((unsigned)f2bf(v.y)) << 16),
            ((unsigned)f2bf(v.z)) | (((unsigned)f2bf(v.w)) << 16));
        return;
    }
    const int row = blockIdx.x - 4096, tid = threadIdx.x;
    const int lane = tid & 63, wave = tid >> 6;
    const float4 v = ((const float4*)(X + (size_t)row * E))[tid];
    float s = v.x + v.y + v.z + v.w;
    float s2 = v.x * v.x + v.y * v.y + v.z * v.z + v.w * v.w;
#pragma unroll
    for (int off = 1; off < 64; off <<= 1) {
        s += __shfl_xor(s, off);
        s2 += __shfl_xor(s2, off);
    }
    __shared__ float red[8];
    if (lane == 0) { red[wave] = s; red[4 + wave] = s2; }
    __syncthreads();
    s = red[0] + red[1] + red[2] + red[3];
    s2 = red[4] + red[5] + red[6] + red[7];
    const float mu = s * (1.f / 1024.f);
    float var = s2 * (1.f / 1024.f) - mu * mu;
    var = fmaxf(var, 0.f);
    const float rs = rsqrtf(var + 1e-5f);
    const float4 wv = ((const float4*)w)[tid];
    const float4 bv = ((const float4*)bb)[tid];
    u16 o0 = f2bf((v.x - mu) * rs * wv.x + bv.x);
    u16 o1 = f2bf((v.y - mu) * rs * wv.y + bv.y);
    u16 o2 = f2bf((v.z - mu) * rs * wv.z + bv.z);
    u16 o3 = f2bf((v.w - mu) * rs * wv.w + bv.w);
    *(uint2*)(xn + (size_t)row * E + tid * 4) =
        make_uint2(((unsigned)o0) | (((unsigned)o1) << 16),
                   ((unsigned)o2) | (((unsigned)o3) << 16));
}

// ---------------- NT GEMM: C[M,1024] = A[M,1024] * B[1024,1024]^T ----------------
// MODE 0: z=0 -> Q (scaled 0.125*log2e), z=1 -> K, both row-major bf16 at
//         outb + z*4096*1024. z=2 -> V written TRANSPOSED to vtout as
//         VT[(b*16+h)][d][n] (per-wave 64n x 64d = one head; transpose via
//         the wave's private 8KB slice of the dead As/Bs LDS, no barrier).
// MODE 1: f32 out = acc + resid + bias
template<int MODE>
__global__ __launch_bounds__(256) void gemm_nt(
    const u16* __restrict__ A, const u16* __restrict__ Wbase,
    u16* __restrict__ outb, u16* __restrict__ vtout, float* __restrict__ outf,
    const float* __restrict__ resid, const float* __restrict__ bias)
{
    __shared__ __align__(16) unsigned char As[128 * 128];
    __shared__ __align__(16) unsigned char Bs[128 * 128];
    const int tid = threadIdx.x;
    const int lane = tid & 63, wave = tid >> 6;
    const int l15 = lane & 15, l4 = lane >> 4;
    const int wm = wave >> 1, wn = wave & 1;
    const int nt = blockIdx.x, mt = blockIdx.y, z = blockIdx.z;
    const u16* Bw = Wbase + (size_t)z * (E * (size_t)E);

    const int lrow8 = lane >> 3;
    const int lchunk = (lane & 7) ^ lrow8;
    const u16* gA = A + (size_t)(mt * 128 + lrow8) * E + lchunk * 8;
    const u16* gB = Bw + (size_t)(nt * 128 + lrow8) * E + lchunk * 8;

    f32x4 acc[4][4] = {};

    for (int kt = 0; kt < 16; ++kt) {
#pragma unroll
        for (int i = 0; i < 4; ++i) {
            const int rb = (i * 4 + wave) * 8;
            GLOAD_LDS16(gA + (size_t)rb * E + kt * 64, As + rb * 128);
            GLOAD_LDS16(gB + (size_t)rb * E + kt * 64, Bs + rb * 128);
        }
        __syncthreads();
#pragma unroll
        for (int ks = 0; ks < 2; ++ks) {
            short8 af[4], bfr[4];
#pragma unroll
            for (int i = 0; i < 4; ++i) {
                int ra = wm * 64 + i * 16 + l15;
                af[i] = *(const short8*)(As + ra * 128 + ((ks * 64 + l4 * 16) ^ ((ra & 7) << 4)));
                int rb2 = wn * 64 + i * 16 + l15;
                bfr[i] = *(const short8*)(Bs + rb2 * 128 + ((ks * 64 + l4 * 16) ^ ((rb2 & 7) << 4)));
            }
#pragma unroll
            for (int i = 0; i < 4; ++i)
#pragma unroll
                for (int j = 0; j < 4; ++j)
                    acc[i][j] = mfma16(af[i], bfr[j], acc[i][j]);
        }
        __syncthreads();
    }

    const int orow0 = mt * 128 + wm * 64, ocol0 = nt * 128 + wn * 64;
    if (MODE == 0) {
        if (z == 2) {
            // ---- fused V transpose: per-wave 64n x 64d tile -> VT[bh][d][n] ----
            unsigned char* wl = (wave < 2) ? (As + wave * 8192) : (Bs + (wave - 2) * 8192);
#pragma unroll
            for (int i = 0; i < 4; ++i)
#pragma unroll
                for (int j = 0; j < 4; ++j) {
                    u16x4 pk;
#pragma unroll
                    for (int r = 0; r < 4; ++r) pk[r] = f2bf(acc[i][j][r]);
                    const int dl = j * 16 + l15;            // d within head
                    const int boff = dl * 128 + ((i * 32 + l4 * 8) ^ ((dl & 7) << 4));
                    *(u16x4*)(wl + boff) = pk;              // T[d][n..n+4)
                }
            asm volatile("s_waitcnt lgkmcnt(0)" ::: "memory");
            const int b2 = mt >> 4, hh = nt * 2 + wn;
            const int n0 = (mt & 15) * 128 + wm * 64;
            u16* vrow = vtout + (size_t)((b2 * 16 + hh) * 64 + lane) * NSEQ + n0;
#pragma unroll
            for (int c = 0; c < 8; ++c) {
                short8 vv = *(const short8*)(wl + lane * 128 + ((c * 16) ^ ((lane & 7) << 4)));
                *(short8*)(vrow + c * 8) = vv;
            }
        } else {
            u16* outz = outb + (size_t)z * (4096 * (size_t)E);
            const float osc = (z == 0) ? 0.18033688f : 1.0f;  // 0.125 * log2(e)
#pragma unroll
            for (int i = 0; i < 4; ++i)
#pragma unroll
                for (int j = 0; j < 4; ++j)
#pragma unroll
                    for (int r = 0; r < 4; ++r) {
                        int row = orow0 + i * 16 + l4 * 4 + r;
                        int col = ocol0 + j * 16 + l15;
                        outz[(size_t)row * E + col] = f2bf(acc[i][j][r] * osc);
                    }
        }
    } else {
#pragma unroll
        for (int i = 0; i < 4; ++i)
#pragma unroll
            for (int j = 0; j < 4; ++j)
#pragma unroll
                for (int r = 0; r < 4; ++r) {
                    int row = orow0 + i * 16 + l4 * 4 + r;
                    int col = ocol0 + j * 16 + l15;
                    size_t idx = (size_t)row * E + col;
                    outf[idx] = acc[i][j][r] + resid[idx] + bias[col];
                }
    }
}

// ---------------- causal flash attention (r7 best: 53.0 us) ----------------
// grid (16 h, 16 j, 2 b), block 256 = 4 waves: sub=wave>>1 (32-q half of a
// 64-q strip), par=wave&1 (64-kv half of a 128-kv round). Strips j and 31-j
// -> exactly 17 rounds/block (uniform). XCD = h%8 (L2-pinned K/V).
// K [128kv][64d] + V^T [64d][128kv] LDS dbuf via global_load_lds w16
// (pre-swizzled source), 1 barrier/round. Parity merge via dead-K-LDS.
__global__ __launch_bounds__(256) void attn_fwd(
    const u16* __restrict__ Q, const u16* __restrict__ K,
    const u16* __restrict__ VT, u16* __restrict__ O)
{
    __shared__ __align__(16) unsigned char Kls[2 * 16384];  // [128 kv][64 d]
    __shared__ __align__(16) unsigned char Vls[2 * 16384];  // [64 d][128 kv]
    __shared__ __align__(16) unsigned char Ps[4 * 4096];    // per-wave P [32 q][64 kv]
    const int tid = threadIdx.x, lane = tid & 63, wave = tid >> 6;
    const int sub = wave >> 1, par = wave & 1;
    const int l15 = lane & 15, l4 = lane >> 4;
    const int h = blockIdx.x, jg = blockIdx.y, b = blockIdx.z;
    const size_t bbase = (size_t)b * NSEQ * E + h * HD;
    const u16* vt = VT + ((size_t)(b * 16 + h) * 64) * NSEQ;  // [d][n]

    unsigned char* Pw = Ps + wave * 4096;
    const int srowK = lane >> 3, kchunk = (lane & 7) ^ srowK;
    const int srowV = lane >> 4, vchunk = (lane & 15) ^ (((wave & 1) << 2) + srowV);

    auto stage = [&](int t, int buf) {
        const u16* Kg = K + bbase + (size_t)(t * 128) * E;
        const u16* vg = vt + t * 128;
        unsigned char* kd = Kls + buf * 16384 + wave * 1024;
        unsigned char* vd = Vls + buf * 16384 + wave * 1024;
#pragma unroll
        for (int i = 0; i < 4; ++i)
            GLOAD_LDS16(Kg + (size_t)(wave * 8 + i * 32 + srowK) * E + kchunk * 8, kd + i * 4096);
#pragma unroll
        for (int i = 0; i < 4; ++i)
            GLOAD_LDS16(vg + (size_t)(wave * 4 + i * 16 + srowV) * NSEQ + vchunk * 8, vd + i * 4096);
    };

    auto run_strip = [&](int jj) {
        const int qw0 = jj * 64 + sub * 32;
        const int R = (jj >> 1) + 1;

        short8 aq[2][2];
#pragma unroll
        for (int qt = 0; qt < 2; ++qt)
#pragma unroll
            for (int ks = 0; ks < 2; ++ks)
                aq[qt][ks] = *(const short8*)(Q + bbase + (size_t)(qw0 + qt * 16 + l15) * E + ks * 32 + l4 * 8);

        f32x4 accO[2][4] = {};
        float mrow[2] = {-5e29f, -5e29f};
        float lrow[2] = {0.f, 0.f};

        stage(0, 0);
        __syncthreads();

        auto step = [&](int t, auto mc) {
            constexpr bool MASK = decltype(mc)::v;
            const int buf = t & 1;
            if (t + 1 < R) stage(t + 1, buf ^ 1);
            const unsigned char* Kc = Kls + buf * 16384;
            const unsigned char* Vc = Vls + buf * 16384;

            f32x4 s[2][4] = {};
#pragma unroll
            for (int kvt = 0; kvt < 4; ++kvt) {
                const int kr = par * 64 + kvt * 16 + l15;
#pragma unroll
                for (int ks = 0; ks < 2; ++ks) {
                    short8 kfr = *(const short8*)(Kc + kr * 128 + ((ks * 64 + l4 * 16) ^ ((kr & 7) << 4)));
                    s[0][kvt] = mfma16(kfr, aq[0][ks], s[0][kvt]);
                    s[1][kvt] = mfma16(kfr, aq[1][ks], s[1][kvt]);
                }
            }

            if constexpr (MASK) {
#pragma unroll
                for (int qt = 0; qt < 2; ++qt) {
                    const int qg = qw0 + qt * 16 + l15;
#pragma unroll
                    for (int kvt = 0; kvt < 4; ++kvt)
#pragma unroll
                        for (int r = 0; r < 4; ++r) {
                            int kvg = t * 128 + par * 64 + kvt * 16 + l4 * 4 + r;
                            if (kvg > qg) s[qt][kvt][r] = -1e30f;
                        }
                }
            }

#pragma unroll
            for (int qt = 0; qt < 2; ++qt) {
                float m0 = fmaxf(fmaxf(s[qt][0][0], s[qt][0][1]), fmaxf(s[qt][0][2], s[qt][0][3]));
                float m1 = fmaxf(fmaxf(s[qt][1][0], s[qt][1][1]), fmaxf(s[qt][1][2], s[qt][1][3]));
                float m2 = fmaxf(fmaxf(s[qt][2][0], s[qt][2][1]), fmaxf(s[qt][2][2], s[qt][2][3]));
                float m3 = fmaxf(fmaxf(s[qt][3][0], s[qt][3][1]), fmaxf(s[qt][3][2], s[qt][3][3]));
                float pm = fmaxf(fmaxf(m0, m1), fmaxf(m2, m3));
                if (__any(pm > mrow[qt] + 8.f)) {
                    pm = fmaxf(pm, __shfl_xor(pm, 16));
                    pm = fmaxf(pm, __shfl_xor(pm, 32));
                    const float mn = fmaxf(mrow[qt], pm);
                    const float sc = exp2f(mrow[qt] - mn);
                    mrow[qt] = mn;
                    lrow[qt] *= sc;
#pragma unroll
                    for (int r = 0; r < 4; ++r) {
                        float scv = __shfl(sc, l4 * 4 + r);
#pragma unroll
                        for (int dt = 0; dt < 4; ++dt) accO[qt][dt][r] *= scv;
                    }
                }
                const int pr = qt * 16 + l15;
                const int sw = (l15 & 7) << 4;
#pragma unroll
                for (int kvt = 0; kvt < 4; ++kvt) {
                    float p0 = exp2f(s[qt][kvt][0] - mrow[qt]);
                    float p1 = exp2f(s[qt][kvt][1] - mrow[qt]);
                    float p2 = exp2f(s[qt][kvt][2] - mrow[qt]);
                    float p3 = exp2f(s[qt][kvt][3] - mrow[qt]);
                    lrow[qt] += (p0 + p1) + (p2 + p3);
                    uint2 pk = make_uint2(cvt_pk_bf16(p0, p1), cvt_pk_bf16(p2, p3));
                    *(uint2*)(Pw + pr * 128 + ((kvt * 32 + l4 * 8) ^ sw)) = pk;
                }
            }

#pragma unroll
            for (int ks2 = 0; ks2 < 2; ++ks2) {
                const int cb = ks2 * 64 + l4 * 16;
                short8 pf0 = *(const short8*)(Pw + l15 * 128 + (cb ^ ((l15 & 7) << 4)));
                short8 pf1 = *(const short8*)(Pw + (16 + l15) * 128 + (cb ^ ((l15 & 7) << 4)));
#pragma unroll
                for (int dt = 0; dt < 4; ++dt) {
                    const int vr = dt * 16 + l15;
                    short8 vfr = *(const short8*)(Vc + vr * 256 + ((par * 128 + cb) ^ ((vr & 7) << 4)));
                    accO[0][dt] = mfma16(pf0, vfr, accO[0][dt]);
                    accO[1][dt] = mfma16(pf1, vfr, accO[1][dt]);
                }
            }
            __syncthreads();
        };

        for (int t = 0; t + 1 < R; ++t) step(t, BC<false>{});
        step(R - 1, BC<true>{});

        f32x4* Mg = (f32x4*)Kls;
        if (par == 1) {
            f32x4 hd;
            hd[0] = mrow[0]; hd[1] = mrow[1]; hd[2] = lrow[0]; hd[3] = lrow[1];
            Mg[(sub * 9) * 64 + lane] = hd;
#pragma unroll
            for (int qt = 0; qt < 2; ++qt)
#pragma unroll
                for (int dt = 0; dt < 4; ++dt)
                    Mg[(sub * 9 + 1 + qt * 4 + dt) * 64 + lane] = accO[qt][dt];
        }
        __syncthreads();
        if (par == 0) {
            f32x4 hd = Mg[(sub * 9) * 64 + lane];
            float scA[2], scB[2];
#pragma unroll
            for (int qt = 0; qt < 2; ++qt) {
                const float mB = hd[qt], lB = hd[2 + qt];
                const float ms = fmaxf(mrow[qt], mB);
                scA[qt] = exp2f(mrow[qt] - ms);
                scB[qt] = exp2f(mB - ms);
                lrow[qt] = lrow[qt] * scA[qt] + lB * scB[qt];
            }
#pragma unroll
            for (int qt = 0; qt < 2; ++qt)
#pragma unroll
                for (int r = 0; r < 4; ++r) {
                    float sa = __shfl(scA[qt], l4 * 4 + r);
                    float sb = __shfl(scB[qt], l4 * 4 + r);
#pragma unroll
                    for (int dt = 0; dt < 4; ++dt) {
                        f32x4 ob = Mg[(sub * 9 + 1 + qt * 4 + dt) * 64 + lane];
                        accO[qt][dt][r] = accO[qt][dt][r] * sa + ob[r] * sb;
                    }
                }
            float linv[2];
#pragma unroll
            for (int qt = 0; qt < 2; ++qt) {
                float tl2 = lrow[qt];
                tl2 += __shfl_xor(tl2, 16);
                tl2 += __shfl_xor(tl2, 32);
                linv[qt] = 1.f / tl2;
            }
#pragma unroll
            for (int rt = 0; rt < 2; ++rt)
#pragma unroll
                for (int r = 0; r < 4; ++r) {
                    float lq = __shfl(linv[rt], l4 * 4 + r);
                    const int qg = qw0 + rt * 16 + l4 * 4 + r;
#pragma unroll
                    for (int dt = 0; dt < 4; ++dt)
                        O[bbase + (size_t)qg * E + dt * 16 + l15] = f2bf(accO[rt][dt][r] * lq);
                }
        }
        __syncthreads();  // protect scratch before next strip's stage(0,0)
    };

    run_strip(jg);
    run_strip(31 - jg);
}

extern "C" void kernel_launch(void* const* d_in, const int* in_sizes, int n_in,
                              void* d_out, int out_size, void* d_ws, size_t ws_size,
                              hipStream_t stream)
{
    const float* x    = (const float*)d_in[0];
    const float* ln_w = (const float*)d_in[1];
    const float* ln_b = (const float*)d_in[2];
    const float* Wq   = (const float*)d_in[3];
    const float* Wk   = (const float*)d_in[4];
    const float* Wv   = (const float*)d_in[5];
    const float* Wo   = (const float*)d_in[6];
    const float* bo   = (const float*)d_in[7];
    float* out = (float*)d_out;

    u16* ws  = (u16*)d_ws;
    u16* Wbf = ws;                                  // 4 * 2^20 bf16
    u16* xn  = Wbf + (size_t)4 * 1024 * 1024;       // 4096*1024
    u16* Qb  = xn + (size_t)4096 * 1024;
    u16* Kb  = Qb + (size_t)4096 * 1024;
    u16* VT  = Kb + (size_t)4096 * 1024;            // V^T written directly by gemm<0> z==2
    u16* Ob  = VT + (size_t)4096 * 1024;

    prep_k<<<dim3(8192), dim3(256), 0, stream>>>(Wq, Wk, Wv, Wo, x, ln_w, ln_b, Wbf, xn);
    gemm_nt<0><<<dim3(8, 32, 3), dim3(256), 0, stream>>>(
        xn, Wbf, Qb, VT, nullptr, nullptr, nullptr);
    attn_fwd<<<dim3(16, 16, 2), dim3(256), 0, stream>>>(Qb, Kb, VT, Ob);
    gemm_nt<1><<<dim3(8, 32, 1), dim3(256), 0, stream>>>(
        Ob, Wbf + (size_t)3 * 1024 * 1024, nullptr, nullptr, out, x, bo);
}

// Round 13
// 127.476 us; speedup vs baseline: 1.0208x; 1.0208x over previous
//
#include <hip/hip_runtime.h>

#define E 1024
#define NSEQ 2048
#define HEADS 16
#define HD 64

typedef unsigned short u16;
typedef short short8 __attribute__((ext_vector_type(8)));
typedef float f32x4 __attribute__((ext_vector_type(4)));
typedef u16 u16x4 __attribute__((ext_vector_type(4)));

template<bool B> struct BC { static constexpr bool v = B; };

#define GLOAD_LDS16(gp, lp)                                        \
    __builtin_amdgcn_global_load_lds(                              \
        (const __attribute__((address_space(1))) void*)(gp),       \
        (__attribute__((address_space(3))) void*)(lp), 16, 0, 0)

__device__ __forceinline__ u16 f2bf(float f) {
    union { float f; unsigned u; } v; v.f = f;
    unsigned r = v.u + 0x7fffu + ((v.u >> 16) & 1u);
    return (u16)(r >> 16);
}

__device__ __forceinline__ unsigned cvt_pk_bf16(float lo, float hi) {
    unsigned r;
    asm("v_cvt_pk_bf16_f32 %0, %1, %2" : "=v"(r) : "v"(lo), "v"(hi));
    return r;
}

__device__ __forceinline__ f32x4 mfma16(short8 a, short8 b, f32x4 c) {
    return __builtin_amdgcn_mfma_f32_16x16x32_bf16(a, b, c, 0, 0, 0);
}

// ---------------- fused: weight f32->bf16 convert + LayerNorm ----------------
__global__ __launch_bounds__(256) void prep_k(
    const float* __restrict__ Wq, const float* __restrict__ Wk,
    const float* __restrict__ Wv, const float* __restrict__ Wo,
    const float* __restrict__ X, const float* __restrict__ w,
    const float* __restrict__ bb, u16* __restrict__ Wbf, u16* __restrict__ xn)
{
    if (blockIdx.x < 4096) {
        const unsigned i = (blockIdx.x * 256u + threadIdx.x) * 4u;
        const unsigned m = i >> 20;
        const float* src = (m == 0) ? Wq : (m == 1) ? Wk : (m == 2) ? Wv : Wo;
        const float4 v = *(const float4*)(src + (i & 0xFFFFFu));
        *(uint2*)(Wbf + i) = make_uint2(
            ((unsigned)f2bf(v.x)) | (((unsigned)f2bf(v.y)) << 16),
            ((unsigned)f2bf(v.z)) | (((unsigned)f2bf(v.w)) << 16));
        return;
    }
    const int row = blockIdx.x - 4096, tid = threadIdx.x;
    const int lane = tid & 63, wave = tid >> 6;
    const float4 v = ((const float4*)(X + (size_t)row * E))[tid];
    float s = v.x + v.y + v.z + v.w;
    float s2 = v.x * v.x + v.y * v.y + v.z * v.z + v.w * v.w;
#pragma unroll
    for (int off = 1; off < 64; off <<= 1) {
        s += __shfl_xor(s, off);
        s2 += __shfl_xor(s2, off);
    }
    __shared__ float red[8];
    if (lane == 0) { red[wave] = s; red[4 + wave] = s2; }
    __syncthreads();
    s = red[0] + red[1] + red[2] + red[3];
    s2 = red[4] + red[5] + red[6] + red[7];
    const float mu = s * (1.f / 1024.f);
    float var = s2 * (1.f / 1024.f) - mu * mu;
    var = fmaxf(var, 0.f);
    const float rs = rsqrtf(var + 1e-5f);
    const float4 wv = ((const float4*)w)[tid];
    const float4 bv = ((const float4*)bb)[tid];
    u16 o0 = f2bf((v.x - mu) * rs * wv.x + bv.x);
    u16 o1 = f2bf((v.y - mu) * rs * wv.y + bv.y);
    u16 o2 = f2bf((v.z - mu) * rs * wv.z + bv.z);
    u16 o3 = f2bf((v.w - mu) * rs * wv.w + bv.w);
    *(uint2*)(xn + (size_t)row * E + tid * 4) =
        make_uint2(((unsigned)o0) | (((unsigned)o1) << 16),
                   ((unsigned)o2) | (((unsigned)o3) << 16));
}

// ---------------- NT GEMM: C[M,1024] = A[M,1024] * B[1024,1024]^T ----------------
// MODE 0: z=0 -> Q (scaled 0.125*log2e), z=1 -> K, both row-major bf16 at
//         outb + z*4096*1024. z=2 -> V written TRANSPOSED to vtout as
//         VT[(b*16+h)][d][n] (per-wave 64n x 64d = one head; transpose via
//         the wave's private 8KB slice of the dead As/Bs LDS, no barrier).
//         Global write is COALESCED: 8 lanes cover one 128B d-row.
// MODE 1: f32 out = acc + resid + bias
template<int MODE>
__global__ __launch_bounds__(256) void gemm_nt(
    const u16* __restrict__ A, const u16* __restrict__ Wbase,
    u16* __restrict__ outb, u16* __restrict__ vtout, float* __restrict__ outf,
    const float* __restrict__ resid, const float* __restrict__ bias)
{
    __shared__ __align__(16) unsigned char As[128 * 128];
    __shared__ __align__(16) unsigned char Bs[128 * 128];
    const int tid = threadIdx.x;
    const int lane = tid & 63, wave = tid >> 6;
    const int l15 = lane & 15, l4 = lane >> 4;
    const int wm = wave >> 1, wn = wave & 1;
    const int nt = blockIdx.x, mt = blockIdx.y, z = blockIdx.z;
    const u16* Bw = Wbase + (size_t)z * (E * (size_t)E);

    const int lrow8 = lane >> 3;
    const int lchunk = (lane & 7) ^ lrow8;
    const u16* gA = A + (size_t)(mt * 128 + lrow8) * E + lchunk * 8;
    const u16* gB = Bw + (size_t)(nt * 128 + lrow8) * E + lchunk * 8;

    f32x4 acc[4][4] = {};

    for (int kt = 0; kt < 16; ++kt) {
#pragma unroll
        for (int i = 0; i < 4; ++i) {
            const int rb = (i * 4 + wave) * 8;
            GLOAD_LDS16(gA + (size_t)rb * E + kt * 64, As + rb * 128);
            GLOAD_LDS16(gB + (size_t)rb * E + kt * 64, Bs + rb * 128);
        }
        __syncthreads();
#pragma unroll
        for (int ks = 0; ks < 2; ++ks) {
            short8 af[4], bfr[4];
#pragma unroll
            for (int i = 0; i < 4; ++i) {
                int ra = wm * 64 + i * 16 + l15;
                af[i] = *(const short8*)(As + ra * 128 + ((ks * 64 + l4 * 16) ^ ((ra & 7) << 4)));
                int rb2 = wn * 64 + i * 16 + l15;
                bfr[i] = *(const short8*)(Bs + rb2 * 128 + ((ks * 64 + l4 * 16) ^ ((rb2 & 7) << 4)));
            }
#pragma unroll
            for (int i = 0; i < 4; ++i)
#pragma unroll
                for (int j = 0; j < 4; ++j)
                    acc[i][j] = mfma16(af[i], bfr[j], acc[i][j]);
        }
        __syncthreads();
    }

    const int orow0 = mt * 128 + wm * 64, ocol0 = nt * 128 + wn * 64;
    if (MODE == 0) {
        if (z == 2) {
            // ---- fused V transpose: per-wave 64n x 64d tile -> VT[bh][d][n] ----
            unsigned char* wl = (wave < 2) ? (As + wave * 8192) : (Bs + (wave - 2) * 8192);
#pragma unroll
            for (int i = 0; i < 4; ++i)
#pragma unroll
                for (int j = 0; j < 4; ++j) {
                    u16x4 pk;
#pragma unroll
                    for (int r = 0; r < 4; ++r) pk[r] = f2bf(acc[i][j][r]);
                    const int dl = j * 16 + l15;            // d within head
                    const int boff = dl * 128 + ((i * 32 + l4 * 8) ^ ((dl & 7) << 4));
                    *(u16x4*)(wl + boff) = pk;              // T[d][n..n+4)
                }
            asm volatile("s_waitcnt lgkmcnt(0)" ::: "memory");
            const int b2 = mt >> 4, hh = nt * 2 + wn;
            const int n0 = (mt & 15) * 128 + wm * 64;
            const int lr = lane >> 3;            // row-in-group 0..7
            const int lc = (lane & 7) * 16;      // byte chunk within 128B row
#pragma unroll
            for (int rr = 0; rr < 8; ++rr) {
                const int d = rr * 8 + lr;
                short8 vv = *(const short8*)(wl + d * 128 + (lc ^ ((d & 7) << 4)));
                u16* vrow = vtout + (size_t)((b2 * 16 + hh) * 64 + d) * NSEQ + n0;
                *(short8*)(vrow + (lc >> 1)) = vv;   // 8 lanes -> 128B contiguous
            }
        } else {
            u16* outz = outb + (size_t)z * (4096 * (size_t)E);
            const float osc = (z == 0) ? 0.18033688f : 1.0f;  // 0.125 * log2(e)
#pragma unroll
            for (int i = 0; i < 4; ++i)
#pragma unroll
                for (int j = 0; j < 4; ++j)
#pragma unroll
                    for (int r = 0; r < 4; ++r) {
                        int row = orow0 + i * 16 + l4 * 4 + r;
                        int col = ocol0 + j * 16 + l15;
                        outz[(size_t)row * E + col] = f2bf(acc[i][j][r] * osc);
                    }
        }
    } else {
#pragma unroll
        for (int i = 0; i < 4; ++i)
#pragma unroll
            for (int j = 0; j < 4; ++j)
#pragma unroll
                for (int r = 0; r < 4; ++r) {
                    int row = orow0 + i * 16 + l4 * 4 + r;
                    int col = ocol0 + j * 16 + l15;
                    size_t idx = (size_t)row * E + col;
                    outf[idx] = acc[i][j][r] + resid[idx] + bias[col];
                }
    }
}

// ---------------- causal flash attention (r7 best: 53.0 us) ----------------
// grid (16 h, 16 j, 2 b), block 256 = 4 waves: sub=wave>>1 (32-q half of a
// 64-q strip), par=wave&1 (64-kv half of a 128-kv round). Strips j and 31-j
// -> exactly 17 rounds/block (uniform). XCD = h%8 (L2-pinned K/V).
// K [128kv][64d] + V^T [64d][128kv] LDS dbuf via global_load_lds w16
// (pre-swizzled source), 1 barrier/round. Parity merge via dead-K-LDS.
__global__ __launch_bounds__(256) void attn_fwd(
    const u16* __restrict__ Q, const u16* __restrict__ K,
    const u16* __restrict__ VT, u16* __restrict__ O)
{
    __shared__ __align__(16) unsigned char Kls[2 * 16384];  // [128 kv][64 d]
    __shared__ __align__(16) unsigned char Vls[2 * 16384];  // [64 d][128 kv]
    __shared__ __align__(16) unsigned char Ps[4 * 4096];    // per-wave P [32 q][64 kv]
    const int tid = threadIdx.x, lane = tid & 63, wave = tid >> 6;
    const int sub = wave >> 1, par = wave & 1;
    const int l15 = lane & 15, l4 = lane >> 4;
    const int h = blockIdx.x, jg = blockIdx.y, b = blockIdx.z;
    const size_t bbase = (size_t)b * NSEQ * E + h * HD;
    const u16* vt = VT + ((size_t)(b * 16 + h) * 64) * NSEQ;  // [d][n]

    unsigned char* Pw = Ps + wave * 4096;
    const int srowK = lane >> 3, kchunk = (lane & 7) ^ srowK;
    const int srowV = lane >> 4, vchunk = (lane & 15) ^ (((wave & 1) << 2) + srowV);

    auto stage = [&](int t, int buf) {
        const u16* Kg = K + bbase + (size_t)(t * 128) * E;
        const u16* vg = vt + t * 128;
        unsigned char* kd = Kls + buf * 16384 + wave * 1024;
        unsigned char* vd = Vls + buf * 16384 + wave * 1024;
#pragma unroll
        for (int i = 0; i < 4; ++i)
            GLOAD_LDS16(Kg + (size_t)(wave * 8 + i * 32 + srowK) * E + kchunk * 8, kd + i * 4096);
#pragma unroll
        for (int i = 0; i < 4; ++i)
            GLOAD_LDS16(vg + (size_t)(wave * 4 + i * 16 + srowV) * NSEQ + vchunk * 8, vd + i * 4096);
    };

    auto run_strip = [&](int jj) {
        const int qw0 = jj * 64 + sub * 32;
        const int R = (jj >> 1) + 1;

        short8 aq[2][2];
#pragma unroll
        for (int qt = 0; qt < 2; ++qt)
#pragma unroll
            for (int ks = 0; ks < 2; ++ks)
                aq[qt][ks] = *(const short8*)(Q + bbase + (size_t)(qw0 + qt * 16 + l15) * E + ks * 32 + l4 * 8);

        f32x4 accO[2][4] = {};
        float mrow[2] = {-5e29f, -5e29f};
        float lrow[2] = {0.f, 0.f};

        stage(0, 0);
        __syncthreads();

        auto step = [&](int t, auto mc) {
            constexpr bool MASK = decltype(mc)::v;
            const int buf = t & 1;
            if (t + 1 < R) stage(t + 1, buf ^ 1);
            const unsigned char* Kc = Kls + buf * 16384;
            const unsigned char* Vc = Vls + buf * 16384;

            f32x4 s[2][4] = {};
#pragma unroll
            for (int kvt = 0; kvt < 4; ++kvt) {
                const int kr = par * 64 + kvt * 16 + l15;
#pragma unroll
                for (int ks = 0; ks < 2; ++ks) {
                    short8 kfr = *(const short8*)(Kc + kr * 128 + ((ks * 64 + l4 * 16) ^ ((kr & 7) << 4)));
                    s[0][kvt] = mfma16(kfr, aq[0][ks], s[0][kvt]);
                    s[1][kvt] = mfma16(kfr, aq[1][ks], s[1][kvt]);
                }
            }

            if constexpr (MASK) {
#pragma unroll
                for (int qt = 0; qt < 2; ++qt) {
                    const int qg = qw0 + qt * 16 + l15;
#pragma unroll
                    for (int kvt = 0; kvt < 4; ++kvt)
#pragma unroll
                        for (int r = 0; r < 4; ++r) {
                            int kvg = t * 128 + par * 64 + kvt * 16 + l4 * 4 + r;
                            if (kvg > qg) s[qt][kvt][r] = -1e30f;
                        }
                }
            }

#pragma unroll
            for (int qt = 0; qt < 2; ++qt) {
                float m0 = fmaxf(fmaxf(s[qt][0][0], s[qt][0][1]), fmaxf(s[qt][0][2], s[qt][0][3]));
                float m1 = fmaxf(fmaxf(s[qt][1][0], s[qt][1][1]), fmaxf(s[qt][1][2], s[qt][1][3]));
                float m2 = fmaxf(fmaxf(s[qt][2][0], s[qt][2][1]), fmaxf(s[qt][2][2], s[qt][2][3]));
                float m3 = fmaxf(fmaxf(s[qt][3][0], s[qt][3][1]), fmaxf(s[qt][3][2], s[qt][3][3]));
                float pm = fmaxf(fmaxf(m0, m1), fmaxf(m2, m3));
                if (__any(pm > mrow[qt] + 8.f)) {
                    pm = fmaxf(pm, __shfl_xor(pm, 16));
                    pm = fmaxf(pm, __shfl_xor(pm, 32));
                    const float mn = fmaxf(mrow[qt], pm);
                    const float sc = exp2f(mrow[qt] - mn);
                    mrow[qt] = mn;
                    lrow[qt] *= sc;
#pragma unroll
                    for (int r = 0; r < 4; ++r) {
                        float scv = __shfl(sc, l4 * 4 + r);
#pragma unroll
                        for (int dt = 0; dt < 4; ++dt) accO[qt][dt][r] *= scv;
                    }
                }
                const int pr = qt * 16 + l15;
                const int sw = (l15 & 7) << 4;
#pragma unroll
                for (int kvt = 0; kvt < 4; ++kvt) {
                    float p0 = exp2f(s[qt][kvt][0] - mrow[qt]);
                    float p1 = exp2f(s[qt][kvt][1] - mrow[qt]);
                    float p2 = exp2f(s[qt][kvt][2] - mrow[qt]);
                    float p3 = exp2f(s[qt][kvt][3] - mrow[qt]);
                    lrow[qt] += (p0 + p1) + (p2 + p3);
                    uint2 pk = make_uint2(cvt_pk_bf16(p0, p1), cvt_pk_bf16(p2, p3));
                    *(uint2*)(Pw + pr * 128 + ((kvt * 32 + l4 * 8) ^ sw)) = pk;
                }
            }

#pragma unroll
            for (int ks2 = 0; ks2 < 2; ++ks2) {
                const int cb = ks2 * 64 + l4 * 16;
                short8 pf0 = *(const short8*)(Pw + l15 * 128 + (cb ^ ((l15 & 7) << 4)));
                short8 pf1 = *(const short8*)(Pw + (16 + l15) * 128 + (cb ^ ((l15 & 7) << 4)));
#pragma unroll
                for (int dt = 0; dt < 4; ++dt) {
                    const int vr = dt * 16 + l15;
                    short8 vfr = *(const short8*)(Vc + vr * 256 + ((par * 128 + cb) ^ ((vr & 7) << 4)));
                    accO[0][dt] = mfma16(pf0, vfr, accO[0][dt]);
                    accO[1][dt] = mfma16(pf1, vfr, accO[1][dt]);
                }
            }
            __syncthreads();
        };

        for (int t = 0; t + 1 < R; ++t) step(t, BC<false>{});
        step(R - 1, BC<true>{});

        f32x4* Mg = (f32x4*)Kls;
        if (par == 1) {
            f32x4 hd;
            hd[0] = mrow[0]; hd[1] = mrow[1]; hd[2] = lrow[0]; hd[3] = lrow[1];
            Mg[(sub * 9) * 64 + lane] = hd;
#pragma unroll
            for (int qt = 0; qt < 2; ++qt)
#pragma unroll
                for (int dt = 0; dt < 4; ++dt)
                    Mg[(sub * 9 + 1 + qt * 4 + dt) * 64 + lane] = accO[qt][dt];
        }
        __syncthreads();
        if (par == 0) {
            f32x4 hd = Mg[(sub * 9) * 64 + lane];
            float scA[2], scB[2];
#pragma unroll
            for (int qt = 0; qt < 2; ++qt) {
                const float mB = hd[qt], lB = hd[2 + qt];
                const float ms = fmaxf(mrow[qt], mB);
                scA[qt] = exp2f(mrow[qt] - ms);
                scB[qt] = exp2f(mB - ms);
                lrow[qt] = lrow[qt] * scA[qt] + lB * scB[qt];
            }
#pragma unroll
            for (int qt = 0; qt < 2; ++qt)
#pragma unroll
                for (int r = 0; r < 4; ++r) {
                    float sa = __shfl(scA[qt], l4 * 4 + r);
                    float sb = __shfl(scB[qt], l4 * 4 + r);
#pragma unroll
                    for (int dt = 0; dt < 4; ++dt) {
                        f32x4 ob = Mg[(sub * 9 + 1 + qt * 4 + dt) * 64 + lane];
                        accO[qt][dt][r] = accO[qt][dt][r] * sa + ob[r] * sb;
                    }
                }
            float linv[2];
#pragma unroll
            for (int qt = 0; qt < 2; ++qt) {
                float tl2 = lrow[qt];
                tl2 += __shfl_xor(tl2, 16);
                tl2 += __shfl_xor(tl2, 32);
                linv[qt] = 1.f / tl2;
            }
#pragma unroll
            for (int rt = 0; rt < 2; ++rt)
#pragma unroll
                for (int r = 0; r < 4; ++r) {
                    float lq = __shfl(linv[rt], l4 * 4 + r);
                    const int qg = qw0 + rt * 16 + l4 * 4 + r;
#pragma unroll
                    for (int dt = 0; dt < 4; ++dt)
                        O[bbase + (size_t)qg * E + dt * 16 + l15] = f2bf(accO[rt][dt][r] * lq);
                }
        }
        __syncthreads();  // protect scratch before next strip's stage(0,0)
    };

    run_strip(jg);
    run_strip(31 - jg);
}

extern "C" void kernel_launch(void* const* d_in, const int* in_sizes, int n_in,
                              void* d_out, int out_size, void* d_ws, size_t ws_size,
                              hipStream_t stream)
{
    const float* x    = (const float*)d_in[0];
    const float* ln_w = (const float*)d_in[1];
    const float* ln_b = (const float*)d_in[2];
    const float* Wq   = (const float*)d_in[3];
    const float* Wk   = (const float*)d_in[4];
    const float* Wv   = (const float*)d_in[5];
    const float* Wo   = (const float*)d_in[6];
    const float* bo   = (const float*)d_in[7];
    float* out = (float*)d_out;

    u16* ws  = (u16*)d_ws;
    u16* Wbf = ws;                                  // 4 * 2^20 bf16
    u16* xn  = Wbf + (size_t)4 * 1024 * 1024;       // 4096*1024
    u16* Qb  = xn + (size_t)4096 * 1024;
    u16* Kb  = Qb + (size_t)4096 * 1024;
    u16* VT  = Kb + (size_t)4096 * 1024;            // V^T written directly by gemm<0> z==2
    u16* Ob  = VT + (size_t)4096 * 1024;

    prep_k<<<dim3(8192), dim3(256), 0, stream>>>(Wq, Wk, Wv, Wo, x, ln_w, ln_b, Wbf, xn);
    gemm_nt<0><<<dim3(8, 32, 3), dim3(256), 0, stream>>>(
        xn, Wbf, Qb, VT, nullptr, nullptr, nullptr);
    attn_fwd<<<dim3(16, 16, 2), dim3(256), 0, stream>>>(Qb, Kb, VT, Ob);
    gemm_nt<1><<<dim3(8, 32, 1), dim3(256), 0, stream>>>(
        Ob, Wbf + (size_t)3 * 1024 * 1024, nullptr, nullptr, out, x, bo);
}

// Round 14
// 120.458 us; speedup vs baseline: 1.0802x; 1.0583x over previous
//
#include <hip/hip_runtime.h>

#define E 1024
#define NSEQ 2048
#define HEADS 16
#define HD 64

typedef unsigned short u16;
typedef short short8 __attribute__((ext_vector_type(8)));
typedef float f32x4 __attribute__((ext_vector_type(4)));

template<bool B> struct BC { static constexpr bool v = B; };

#define GLOAD_LDS16(gp, lp)                                        \
    __builtin_amdgcn_global_load_lds(                              \
        (const __attribute__((address_space(1))) void*)(gp),       \
        (__attribute__((address_space(3))) void*)(lp), 16, 0, 0)

__device__ __forceinline__ u16 f2bf(float f) {
    union { float f; unsigned u; } v; v.f = f;
    unsigned r = v.u + 0x7fffu + ((v.u >> 16) & 1u);
    return (u16)(r >> 16);
}

__device__ __forceinline__ unsigned cvt_pk_bf16(float lo, float hi) {
    unsigned r;
    asm("v_cvt_pk_bf16_f32 %0, %1, %2" : "=v"(r) : "v"(lo), "v"(hi));
    return r;
}

__device__ __forceinline__ f32x4 mfma16(short8 a, short8 b, f32x4 c) {
    return __builtin_amdgcn_mfma_f32_16x16x32_bf16(a, b, c, 0, 0, 0);
}

// ---------------- fused: weight f32->bf16 convert + LayerNorm ----------------
__global__ __launch_bounds__(256) void prep_k(
    const float* __restrict__ Wq, const float* __restrict__ Wk,
    const float* __restrict__ Wv, const float* __restrict__ Wo,
    const float* __restrict__ X, const float* __restrict__ w,
    const float* __restrict__ bb, u16* __restrict__ Wbf, u16* __restrict__ xn)
{
    if (blockIdx.x < 4096) {
        const unsigned i = (blockIdx.x * 256u + threadIdx.x) * 4u;
        const unsigned m = i >> 20;
        const float* src = (m == 0) ? Wq : (m == 1) ? Wk : (m == 2) ? Wv : Wo;
        const float4 v = *(const float4*)(src + (i & 0xFFFFFu));
        *(uint2*)(Wbf + i) = make_uint2(
            ((unsigned)f2bf(v.x)) | (((unsigned)f2bf(v.y)) << 16),
            ((unsigned)f2bf(v.z)) | (((unsigned)f2bf(v.w)) << 16));
        return;
    }
    const int row = blockIdx.x - 4096, tid = threadIdx.x;
    const int lane = tid & 63, wave = tid >> 6;
    const float4 v = ((const float4*)(X + (size_t)row * E))[tid];
    float s = v.x + v.y + v.z + v.w;
    float s2 = v.x * v.x + v.y * v.y + v.z * v.z + v.w * v.w;
#pragma unroll
    for (int off = 1; off < 64; off <<= 1) {
        s += __shfl_xor(s, off);
        s2 += __shfl_xor(s2, off);
    }
    __shared__ float red[8];
    if (lane == 0) { red[wave] = s; red[4 + wave] = s2; }
    __syncthreads();
    s = red[0] + red[1] + red[2] + red[3];
    s2 = red[4] + red[5] + red[6] + red[7];
    const float mu = s * (1.f / 1024.f);
    float var = s2 * (1.f / 1024.f) - mu * mu;
    var = fmaxf(var, 0.f);
    const float rs = rsqrtf(var + 1e-5f);
    const float4 wv = ((const float4*)w)[tid];
    const float4 bv = ((const float4*)bb)[tid];
    u16 o0 = f2bf((v.x - mu) * rs * wv.x + bv.x);
    u16 o1 = f2bf((v.y - mu) * rs * wv.y + bv.y);
    u16 o2 = f2bf((v.z - mu) * rs * wv.z + bv.z);
    u16 o3 = f2bf((v.w - mu) * rs * wv.w + bv.w);
    *(uint2*)(xn + (size_t)row * E + tid * 4) =
        make_uint2(((unsigned)o0) | (((unsigned)o1) << 16),
                   ((unsigned)o2) | (((unsigned)o3) << 16));
}

// ---------------- V transpose: V[b][n][h*64+d] -> VT[(b*16+h)][d][n] ----------------
__global__ __launch_bounds__(256) void vtrans(
    const u16* __restrict__ Vb, u16* __restrict__ VT)
{
    __shared__ u16 tl[64][65];
    const int t = threadIdx.x;
    const int ntile = blockIdx.x, bh = blockIdx.y;
    const int b = bh >> 4, h = bh & 15;
    const int n0 = ntile * 64;
    {
        const int nl = t >> 2;
        const u16* src = Vb + ((size_t)b * NSEQ + n0 + nl) * E + h * 64;
#pragma unroll
        for (int u = 0; u < 2; ++u) {
            const int d0 = (t & 3) * 16 + u * 8;
            short8 v = *(const short8*)(src + d0);
#pragma unroll
            for (int j = 0; j < 8; ++j) tl[nl][d0 + j] = (u16)v[j];
        }
    }
    __syncthreads();
    {
        const int d = t >> 2, nc = (t & 3) * 16;
        u16* dst = VT + ((size_t)bh * 64 + d) * NSEQ + n0 + nc;
#pragma unroll
        for (int u = 0; u < 2; ++u) {
            short8 o;
#pragma unroll
            for (int j = 0; j < 8; ++j) o[j] = (short)tl[nc + u * 8 + j][d];
            *(short8*)(dst + u * 8) = o;
        }
    }
}

// ---------------- NT GEMM: C[M,1024] = A[M,1024] * B[1024,1024]^T ----------------
template<int MODE>
__global__ __launch_bounds__(256) void gemm_nt(
    const u16* __restrict__ A, const u16* __restrict__ Wbase,
    u16* __restrict__ outb, float* __restrict__ outf,
    const float* __restrict__ resid, const float* __restrict__ bias)
{
    __shared__ __align__(16) unsigned char As[128 * 128];
    __shared__ __align__(16) unsigned char Bs[128 * 128];
    const int tid = threadIdx.x;
    const int lane = tid & 63, wave = tid >> 6;
    const int l15 = lane & 15, l4 = lane >> 4;
    const int wm = wave >> 1, wn = wave & 1;
    const int nt = blockIdx.x, mt = blockIdx.y, z = blockIdx.z;
    const u16* Bw = Wbase + (size_t)z * (E * (size_t)E);

    const int lrow8 = lane >> 3;
    const int lchunk = (lane & 7) ^ lrow8;
    const u16* gA = A + (size_t)(mt * 128 + lrow8) * E + lchunk * 8;
    const u16* gB = Bw + (size_t)(nt * 128 + lrow8) * E + lchunk * 8;

    f32x4 acc[4][4] = {};

    for (int kt = 0; kt < 16; ++kt) {
#pragma unroll
        for (int i = 0; i < 4; ++i) {
            const int rb = (i * 4 + wave) * 8;
            GLOAD_LDS16(gA + (size_t)rb * E + kt * 64, As + rb * 128);
            GLOAD_LDS16(gB + (size_t)rb * E + kt * 64, Bs + rb * 128);
        }
        __syncthreads();
#pragma unroll
        for (int ks = 0; ks < 2; ++ks) {
            short8 af[4], bfr[4];
#pragma unroll
            for (int i = 0; i < 4; ++i) {
                int ra = wm * 64 + i * 16 + l15;
                af[i] = *(const short8*)(As + ra * 128 + ((ks * 64 + l4 * 16) ^ ((ra & 7) << 4)));
                int rb2 = wn * 64 + i * 16 + l15;
                bfr[i] = *(const short8*)(Bs + rb2 * 128 + ((ks * 64 + l4 * 16) ^ ((rb2 & 7) << 4)));
            }
#pragma unroll
            for (int i = 0; i < 4; ++i)
#pragma unroll
                for (int j = 0; j < 4; ++j)
                    acc[i][j] = mfma16(af[i], bfr[j], acc[i][j]);
        }
        __syncthreads();
    }

    const int orow0 = mt * 128 + wm * 64, ocol0 = nt * 128 + wn * 64;
    if (MODE == 0) {
        u16* outz = outb + (size_t)z * (4096 * (size_t)E);
        const float osc = (z == 0) ? 0.18033688f : 1.0f;  // 0.125 * log2(e)
#pragma unroll
        for (int i = 0; i < 4; ++i)
#pragma unroll
            for (int j = 0; j < 4; ++j)
#pragma unroll
                for (int r = 0; r < 4; ++r) {
                    int row = orow0 + i * 16 + l4 * 4 + r;
                    int col = ocol0 + j * 16 + l15;
                    outz[(size_t)row * E + col] = f2bf(acc[i][j][r] * osc);
                }
    } else {
#pragma unroll
        for (int i = 0; i < 4; ++i)
#pragma unroll
            for (int j = 0; j < 4; ++j)
#pragma unroll
                for (int r = 0; r < 4; ++r) {
                    int row = orow0 + i * 16 + l4 * 4 + r;
                    int col = ocol0 + j * 16 + l15;
                    size_t idx = (size_t)row * E + col;
                    outf[idx] = acc[i][j][r] + resid[idx] + bias[col];
                }
    }
}

// ---------------- causal flash attention (r7 best: 53.0 us) ----------------
// grid (16 h, 16 j, 2 b), block 256 = 4 waves: sub=wave>>1 (32-q half of a
// 64-q strip), par=wave&1 (64-kv half of a 128-kv round). Strips j and 31-j
// -> exactly 17 rounds/block (uniform). XCD = h%8 (L2-pinned K/V).
// K [128kv][64d] + V^T [64d][128kv] LDS dbuf via global_load_lds w16
// (pre-swizzled source), 1 barrier/round. Parity merge via dead-K-LDS.
__global__ __launch_bounds__(256) void attn_fwd(
    const u16* __restrict__ Q, const u16* __restrict__ K,
    const u16* __restrict__ VT, u16* __restrict__ O)
{
    __shared__ __align__(16) unsigned char Kls[2 * 16384];  // [128 kv][64 d]
    __shared__ __align__(16) unsigned char Vls[2 * 16384];  // [64 d][128 kv]
    __shared__ __align__(16) unsigned char Ps[4 * 4096];    // per-wave P [32 q][64 kv]
    const int tid = threadIdx.x, lane = tid & 63, wave = tid >> 6;
    const int sub = wave >> 1, par = wave & 1;
    const int l15 = lane & 15, l4 = lane >> 4;
    const int h = blockIdx.x, jg = blockIdx.y, b = blockIdx.z;
    const size_t bbase = (size_t)b * NSEQ * E + h * HD;
    const u16* vt = VT + ((size_t)(b * 16 + h) * 64) * NSEQ;  // [d][n]

    unsigned char* Pw = Ps + wave * 4096;
    const int srowK = lane >> 3, kchunk = (lane & 7) ^ srowK;
    const int srowV = lane >> 4, vchunk = (lane & 15) ^ (((wave & 1) << 2) + srowV);

    auto stage = [&](int t, int buf) {
        const u16* Kg = K + bbase + (size_t)(t * 128) * E;
        const u16* vg = vt + t * 128;
        unsigned char* kd = Kls + buf * 16384 + wave * 1024;
        unsigned char* vd = Vls + buf * 16384 + wave * 1024;
#pragma unroll
        for (int i = 0; i < 4; ++i)
            GLOAD_LDS16(Kg + (size_t)(wave * 8 + i * 32 + srowK) * E + kchunk * 8, kd + i * 4096);
#pragma unroll
        for (int i = 0; i < 4; ++i)
            GLOAD_LDS16(vg + (size_t)(wave * 4 + i * 16 + srowV) * NSEQ + vchunk * 8, vd + i * 4096);
    };

    auto run_strip = [&](int jj) {
        const int qw0 = jj * 64 + sub * 32;
        const int R = (jj >> 1) + 1;

        short8 aq[2][2];
#pragma unroll
        for (int qt = 0; qt < 2; ++qt)
#pragma unroll
            for (int ks = 0; ks < 2; ++ks)
                aq[qt][ks] = *(const short8*)(Q + bbase + (size_t)(qw0 + qt * 16 + l15) * E + ks * 32 + l4 * 8);

        f32x4 accO[2][4] = {};
        float mrow[2] = {-5e29f, -5e29f};
        float lrow[2] = {0.f, 0.f};

        stage(0, 0);
        __syncthreads();

        auto step = [&](int t, auto mc) {
            constexpr bool MASK = decltype(mc)::v;
            const int buf = t & 1;
            if (t + 1 < R) stage(t + 1, buf ^ 1);
            const unsigned char* Kc = Kls + buf * 16384;
            const unsigned char* Vc = Vls + buf * 16384;

            f32x4 s[2][4] = {};
#pragma unroll
            for (int kvt = 0; kvt < 4; ++kvt) {
                const int kr = par * 64 + kvt * 16 + l15;
#pragma unroll
                for (int ks = 0; ks < 2; ++ks) {
                    short8 kfr = *(const short8*)(Kc + kr * 128 + ((ks * 64 + l4 * 16) ^ ((kr & 7) << 4)));
                    s[0][kvt] = mfma16(kfr, aq[0][ks], s[0][kvt]);
                    s[1][kvt] = mfma16(kfr, aq[1][ks], s[1][kvt]);
                }
            }

            if constexpr (MASK) {
#pragma unroll
                for (int qt = 0; qt < 2; ++qt) {
                    const int qg = qw0 + qt * 16 + l15;
#pragma unroll
                    for (int kvt = 0; kvt < 4; ++kvt)
#pragma unroll
                        for (int r = 0; r < 4; ++r) {
                            int kvg = t * 128 + par * 64 + kvt * 16 + l4 * 4 + r;
                            if (kvg > qg) s[qt][kvt][r] = -1e30f;
                        }
                }
            }

#pragma unroll
            for (int qt = 0; qt < 2; ++qt) {
                float m0 = fmaxf(fmaxf(s[qt][0][0], s[qt][0][1]), fmaxf(s[qt][0][2], s[qt][0][3]));
                float m1 = fmaxf(fmaxf(s[qt][1][0], s[qt][1][1]), fmaxf(s[qt][1][2], s[qt][1][3]));
                float m2 = fmaxf(fmaxf(s[qt][2][0], s[qt][2][1]), fmaxf(s[qt][2][2], s[qt][2][3]));
                float m3 = fmaxf(fmaxf(s[qt][3][0], s[qt][3][1]), fmaxf(s[qt][3][2], s[qt][3][3]));
                float pm = fmaxf(fmaxf(m0, m1), fmaxf(m2, m3));
                if (__any(pm > mrow[qt] + 8.f)) {
                    pm = fmaxf(pm, __shfl_xor(pm, 16));
                    pm = fmaxf(pm, __shfl_xor(pm, 32));
                    const float mn = fmaxf(mrow[qt], pm);
                    const float sc = exp2f(mrow[qt] - mn);
                    mrow[qt] = mn;
                    lrow[qt] *= sc;
#pragma unroll
                    for (int r = 0; r < 4; ++r) {
                        float scv = __shfl(sc, l4 * 4 + r);
#pragma unroll
                        for (int dt = 0; dt < 4; ++dt) accO[qt][dt][r] *= scv;
                    }
                }
                const int pr = qt * 16 + l15;
                const int sw = (l15 & 7) << 4;
#pragma unroll
                for (int kvt = 0; kvt < 4; ++kvt) {
                    float p0 = exp2f(s[qt][kvt][0] - mrow[qt]);
                    float p1 = exp2f(s[qt][kvt][1] - mrow[qt]);
                    float p2 = exp2f(s[qt][kvt][2] - mrow[qt]);
                    float p3 = exp2f(s[qt][kvt][3] - mrow[qt]);
                    lrow[qt] += (p0 + p1) + (p2 + p3);
                    uint2 pk = make_uint2(cvt_pk_bf16(p0, p1), cvt_pk_bf16(p2, p3));
                    *(uint2*)(Pw + pr * 128 + ((kvt * 32 + l4 * 8) ^ sw)) = pk;
                }
            }

#pragma unroll
            for (int ks2 = 0; ks2 < 2; ++ks2) {
                const int cb = ks2 * 64 + l4 * 16;
                short8 pf0 = *(const short8*)(Pw + l15 * 128 + (cb ^ ((l15 & 7) << 4)));
                short8 pf1 = *(const short8*)(Pw + (16 + l15) * 128 + (cb ^ ((l15 & 7) << 4)));
#pragma unroll
                for (int dt = 0; dt < 4; ++dt) {
                    const int vr = dt * 16 + l15;
                    short8 vfr = *(const short8*)(Vc + vr * 256 + ((par * 128 + cb) ^ ((vr & 7) << 4)));
                    accO[0][dt] = mfma16(pf0, vfr, accO[0][dt]);
                    accO[1][dt] = mfma16(pf1, vfr, accO[1][dt]);
                }
            }
            __syncthreads();
        };

        for (int t = 0; t + 1 < R; ++t) step(t, BC<false>{});
        step(R - 1, BC<true>{});

        f32x4* Mg = (f32x4*)Kls;
        if (par == 1) {
            f32x4 hd;
            hd[0] = mrow[0]; hd[1] = mrow[1]; hd[2] = lrow[0]; hd[3] = lrow[1];
            Mg[(sub * 9) * 64 + lane] = hd;
#pragma unroll
            for (int qt = 0; qt < 2; ++qt)
#pragma unroll
                for (int dt = 0; dt < 4; ++dt)
                    Mg[(sub * 9 + 1 + qt * 4 + dt) * 64 + lane] = accO[qt][dt];
        }
        __syncthreads();
        if (par == 0) {
            f32x4 hd = Mg[(sub * 9) * 64 + lane];
            float scA[2], scB[2];
#pragma unroll
            for (int qt = 0; qt < 2; ++qt) {
                const float mB = hd[qt], lB = hd[2 + qt];
                const float ms = fmaxf(mrow[qt], mB);
                scA[qt] = exp2f(mrow[qt] - ms);
                scB[qt] = exp2f(mB - ms);
                lrow[qt] = lrow[qt] * scA[qt] + lB * scB[qt];
            }
#pragma unroll
            for (int qt = 0; qt < 2; ++qt)
#pragma unroll
                for (int r = 0; r < 4; ++r) {
                    float sa = __shfl(scA[qt], l4 * 4 + r);
                    float sb = __shfl(scB[qt], l4 * 4 + r);
#pragma unroll
                    for (int dt = 0; dt < 4; ++dt) {
                        f32x4 ob = Mg[(sub * 9 + 1 + qt * 4 + dt) * 64 + lane];
                        accO[qt][dt][r] = accO[qt][dt][r] * sa + ob[r] * sb;
                    }
                }
            float linv[2];
#pragma unroll
            for (int qt = 0; qt < 2; ++qt) {
                float tl2 = lrow[qt];
                tl2 += __shfl_xor(tl2, 16);
                tl2 += __shfl_xor(tl2, 32);
                linv[qt] = 1.f / tl2;
            }
#pragma unroll
            for (int rt = 0; rt < 2; ++rt)
#pragma unroll
                for (int r = 0; r < 4; ++r) {
                    float lq = __shfl(linv[rt], l4 * 4 + r);
                    const int qg = qw0 + rt * 16 + l4 * 4 + r;
#pragma unroll
                    for (int dt = 0; dt < 4; ++dt)
                        O[bbase + (size_t)qg * E + dt * 16 + l15] = f2bf(accO[rt][dt][r] * lq);
                }
        }
        __syncthreads();  // protect scratch before next strip's stage(0,0)
    };

    run_strip(jg);
    run_strip(31 - jg);
}

extern "C" void kernel_launch(void* const* d_in, const int* in_sizes, int n_in,
                              void* d_out, int out_size, void* d_ws, size_t ws_size,
                              hipStream_t stream)
{
    const float* x    = (const float*)d_in[0];
    const float* ln_w = (const float*)d_in[1];
    const float* ln_b = (const float*)d_in[2];
    const float* Wq   = (const float*)d_in[3];
    const float* Wk   = (const float*)d_in[4];
    const float* Wv   = (const float*)d_in[5];
    const float* Wo   = (const float*)d_in[6];
    const float* bo   = (const float*)d_in[7];
    float* out = (float*)d_out;

    u16* ws  = (u16*)d_ws;
    u16* Wbf = ws;                                  // 4 * 2^20 bf16
    u16* xn  = Wbf + (size_t)4 * 1024 * 1024;       // 4096*1024 (reused as VT)
    u16* Qb  = xn + (size_t)4096 * 1024;
    u16* Kb  = Qb + (size_t)4096 * 1024;
    u16* Vb  = Kb + (size_t)4096 * 1024;
    u16* Ob  = Vb + (size_t)4096 * 1024;
    u16* VT  = xn;  // alias: xn dead after gemm<0>; VT = [32 bh][64 d][2048 n]

    prep_k<<<dim3(8192), dim3(256), 0, stream>>>(Wq, Wk, Wv, Wo, x, ln_w, ln_b, Wbf, xn);
    gemm_nt<0><<<dim3(8, 32, 3), dim3(256), 0, stream>>>(
        xn, Wbf, Qb, nullptr, nullptr, nullptr);
    vtrans<<<dim3(32, 32), dim3(256), 0, stream>>>(Vb, VT);
    attn_fwd<<<dim3(16, 16, 2), dim3(256), 0, stream>>>(Qb, Kb, VT, Ob);
    gemm_nt<1><<<dim3(8, 32, 1), dim3(256), 0, stream>>>(
        Ob, Wbf + (size_t)3 * 1024 * 1024, nullptr, out, x, bo);
}

// Round 15
// 115.932 us; speedup vs baseline: 1.1224x; 1.0390x over previous
//
#include <hip/hip_runtime.h>

#define E 1024
#define NSEQ 2048
#define HEADS 16
#define HD 64

typedef unsigned short u16;
typedef short short8 __attribute__((ext_vector_type(8)));
typedef float f32x4 __attribute__((ext_vector_type(4)));

template<bool B> struct BC { static constexpr bool v = B; };

#define GLOAD_LDS16(gp, lp)                                        \
    __builtin_amdgcn_global_load_lds(                              \
        (const __attribute__((address_space(1))) void*)(gp),       \
        (__attribute__((address_space(3))) void*)(lp), 16, 0, 0)

__device__ __forceinline__ u16 f2bf(float f) {
    union { float f; unsigned u; } v; v.f = f;
    unsigned r = v.u + 0x7fffu + ((v.u >> 16) & 1u);
    return (u16)(r >> 16);
}

__device__ __forceinline__ unsigned cvt_pk_bf16(float lo, float hi) {
    unsigned r;
    asm("v_cvt_pk_bf16_f32 %0, %1, %2" : "=v"(r) : "v"(lo), "v"(hi));
    return r;
}

__device__ __forceinline__ f32x4 mfma16(short8 a, short8 b, f32x4 c) {
    return __builtin_amdgcn_mfma_f32_16x16x32_bf16(a, b, c, 0, 0, 0);
}

// ---------------- fused: weight f32->bf16 convert + LayerNorm ----------------
__global__ __launch_bounds__(256) void prep_k(
    const float* __restrict__ Wq, const float* __restrict__ Wk,
    const float* __restrict__ Wv, const float* __restrict__ Wo,
    const float* __restrict__ X, const float* __restrict__ w,
    const float* __restrict__ bb, u16* __restrict__ Wbf, u16* __restrict__ xn)
{
    if (blockIdx.x < 4096) {
        const unsigned i = (blockIdx.x * 256u + threadIdx.x) * 4u;
        const unsigned m = i >> 20;
        const float* src = (m == 0) ? Wq : (m == 1) ? Wk : (m == 2) ? Wv : Wo;
        const float4 v = *(const float4*)(src + (i & 0xFFFFFu));
        *(uint2*)(Wbf + i) = make_uint2(
            ((unsigned)f2bf(v.x)) | (((unsigned)f2bf(v.y)) << 16),
            ((unsigned)f2bf(v.z)) | (((unsigned)f2bf(v.w)) << 16));
        return;
    }
    const int row = blockIdx.x - 4096, tid = threadIdx.x;
    const int lane = tid & 63, wave = tid >> 6;
    const float4 v = ((const float4*)(X + (size_t)row * E))[tid];
    float s = v.x + v.y + v.z + v.w;
    float s2 = v.x * v.x + v.y * v.y + v.z * v.z + v.w * v.w;
#pragma unroll
    for (int off = 1; off < 64; off <<= 1) {
        s += __shfl_xor(s, off);
        s2 += __shfl_xor(s2, off);
    }
    __shared__ float red[8];
    if (lane == 0) { red[wave] = s; red[4 + wave] = s2; }
    __syncthreads();
    s = red[0] + red[1] + red[2] + red[3];
    s2 = red[4] + red[5] + red[6] + red[7];
    const float mu = s * (1.f / 1024.f);
    float var = s2 * (1.f / 1024.f) - mu * mu;
    var = fmaxf(var, 0.f);
    const float rs = rsqrtf(var + 1e-5f);
    const float4 wv = ((const float4*)w)[tid];
    const float4 bv = ((const float4*)bb)[tid];
    u16 o0 = f2bf((v.x - mu) * rs * wv.x + bv.x);
    u16 o1 = f2bf((v.y - mu) * rs * wv.y + bv.y);
    u16 o2 = f2bf((v.z - mu) * rs * wv.z + bv.z);
    u16 o3 = f2bf((v.w - mu) * rs * wv.w + bv.w);
    *(uint2*)(xn + (size_t)row * E + tid * 4) =
        make_uint2(((unsigned)o0) | (((unsigned)o1) << 16),
                   ((unsigned)o2) | (((unsigned)o3) << 16));
}

// ---------------- V transpose: V[b][n][h*64+d] -> VT[(b*16+h)][d][n] ----------------
__global__ __launch_bounds__(256) void vtrans(
    const u16* __restrict__ Vb, u16* __restrict__ VT)
{
    __shared__ u16 tl[64][65];
    const int t = threadIdx.x;
    const int ntile = blockIdx.x, bh = blockIdx.y;
    const int b = bh >> 4, h = bh & 15;
    const int n0 = ntile * 64;
    {
        const int nl = t >> 2;
        const u16* src = Vb + ((size_t)b * NSEQ + n0 + nl) * E + h * 64;
#pragma unroll
        for (int u = 0; u < 2; ++u) {
            const int d0 = (t & 3) * 16 + u * 8;
            short8 v = *(const short8*)(src + d0);
#pragma unroll
            for (int j = 0; j < 8; ++j) tl[nl][d0 + j] = (u16)v[j];
        }
    }
    __syncthreads();
    {
        const int d = t >> 2, nc = (t & 3) * 16;
        u16* dst = VT + ((size_t)bh * 64 + d) * NSEQ + n0 + nc;
#pragma unroll
        for (int u = 0; u < 2; ++u) {
            short8 o;
#pragma unroll
            for (int j = 0; j < 8; ++j) o[j] = (short)tl[nc + u * 8 + j][d];
            *(short8*)(dst + u * 8) = o;
        }
    }
}

// ---------------- NT GEMM (QKV): C[4096,1024] = A * W_z^T, 128x128 tile ----------------
__global__ __launch_bounds__(256) void gemm_nt0(
    const u16* __restrict__ A, const u16* __restrict__ Wbase,
    u16* __restrict__ outb)
{
    __shared__ __align__(16) unsigned char As[128 * 128];
    __shared__ __align__(16) unsigned char Bs[128 * 128];
    const int tid = threadIdx.x;
    const int lane = tid & 63, wave = tid >> 6;
    const int l15 = lane & 15, l4 = lane >> 4;
    const int wm = wave >> 1, wn = wave & 1;
    const int nt = blockIdx.x, mt = blockIdx.y, z = blockIdx.z;
    const u16* Bw = Wbase + (size_t)z * (E * (size_t)E);

    const int lrow8 = lane >> 3;
    const int lchunk = (lane & 7) ^ lrow8;
    const u16* gA = A + (size_t)(mt * 128 + lrow8) * E + lchunk * 8;
    const u16* gB = Bw + (size_t)(nt * 128 + lrow8) * E + lchunk * 8;

    f32x4 acc[4][4] = {};

    for (int kt = 0; kt < 16; ++kt) {
#pragma unroll
        for (int i = 0; i < 4; ++i) {
            const int rb = (i * 4 + wave) * 8;
            GLOAD_LDS16(gA + (size_t)rb * E + kt * 64, As + rb * 128);
            GLOAD_LDS16(gB + (size_t)rb * E + kt * 64, Bs + rb * 128);
        }
        __syncthreads();
#pragma unroll
        for (int ks = 0; ks < 2; ++ks) {
            short8 af[4], bfr[4];
#pragma unroll
            for (int i = 0; i < 4; ++i) {
                int ra = wm * 64 + i * 16 + l15;
                af[i] = *(const short8*)(As + ra * 128 + ((ks * 64 + l4 * 16) ^ ((ra & 7) << 4)));
                int rb2 = wn * 64 + i * 16 + l15;
                bfr[i] = *(const short8*)(Bs + rb2 * 128 + ((ks * 64 + l4 * 16) ^ ((rb2 & 7) << 4)));
            }
#pragma unroll
            for (int i = 0; i < 4; ++i)
#pragma unroll
                for (int j = 0; j < 4; ++j)
                    acc[i][j] = mfma16(af[i], bfr[j], acc[i][j]);
        }
        __syncthreads();
    }

    const int orow0 = mt * 128 + wm * 64, ocol0 = nt * 128 + wn * 64;
    u16* outz = outb + (size_t)z * (4096 * (size_t)E);
    const float osc = (z == 0) ? 0.18033688f : 1.0f;  // 0.125 * log2(e)
#pragma unroll
    for (int i = 0; i < 4; ++i)
#pragma unroll
        for (int j = 0; j < 4; ++j)
#pragma unroll
            for (int r = 0; r < 4; ++r) {
                int row = orow0 + i * 16 + l4 * 4 + r;
                int col = ocol0 + j * 16 + l15;
                outz[(size_t)row * E + col] = f2bf(acc[i][j][r] * osc);
            }
}

// ---------------- output projection: 64x128 tile, grid (8,64) = 2 blocks/CU ----------------
// out = O @ Wo^T + resid + bias. Fixes gemm<1>'s 1-block/CU occupancy hole.
__global__ __launch_bounds__(256) void gemm_nt1(
    const u16* __restrict__ A, const u16* __restrict__ Bw,
    float* __restrict__ outf, const float* __restrict__ resid,
    const float* __restrict__ bias)
{
    __shared__ __align__(16) unsigned char As[64 * 128];    // 64 rows x 64 bf16
    __shared__ __align__(16) unsigned char Bs[128 * 128];   // 128 cols x 64 bf16
    const int tid = threadIdx.x;
    const int lane = tid & 63, wave = tid >> 6;
    const int l15 = lane & 15, l4 = lane >> 4;
    const int nt = blockIdx.x, mt = blockIdx.y;

    const int lrow8 = lane >> 3;
    const int lchunk = (lane & 7) ^ lrow8;
    const u16* gA = A + (size_t)(mt * 64 + lrow8) * E + lchunk * 8;
    const u16* gB = Bw + (size_t)(nt * 128 + lrow8) * E + lchunk * 8;

    f32x4 acc[4][2] = {};

    for (int kt = 0; kt < 16; ++kt) {
#pragma unroll
        for (int i = 0; i < 2; ++i) {    // A: rows wave*8 + i*32 (+0..7)
            const int rb = (i * 4 + wave) * 8;
            GLOAD_LDS16(gA + (size_t)rb * E + kt * 64, As + rb * 128);
        }
#pragma unroll
        for (int i = 0; i < 4; ++i) {    // B: rows wave*8 + i*32 (+0..7)
            const int rb = (i * 4 + wave) * 8;
            GLOAD_LDS16(gB + (size_t)rb * E + kt * 64, Bs + rb * 128);
        }
        __syncthreads();
#pragma unroll
        for (int ks = 0; ks < 2; ++ks) {
            short8 af[4], bfr[2];
#pragma unroll
            for (int i = 0; i < 4; ++i) {
                int ra = i * 16 + l15;
                af[i] = *(const short8*)(As + ra * 128 + ((ks * 64 + l4 * 16) ^ ((ra & 7) << 4)));
            }
#pragma unroll
            for (int j = 0; j < 2; ++j) {
                int rb2 = wave * 32 + j * 16 + l15;
                bfr[j] = *(const short8*)(Bs + rb2 * 128 + ((ks * 64 + l4 * 16) ^ ((rb2 & 7) << 4)));
            }
#pragma unroll
            for (int i = 0; i < 4; ++i)
#pragma unroll
                for (int j = 0; j < 2; ++j)
                    acc[i][j] = mfma16(af[i], bfr[j], acc[i][j]);
        }
        __syncthreads();
    }

    const int orow0 = mt * 64, ocol0 = nt * 128 + wave * 32;
#pragma unroll
    for (int i = 0; i < 4; ++i)
#pragma unroll
        for (int j = 0; j < 2; ++j)
#pragma unroll
            for (int r = 0; r < 4; ++r) {
                int row = orow0 + i * 16 + l4 * 4 + r;
                int col = ocol0 + j * 16 + l15;
                size_t idx = (size_t)row * E + col;
                outf[idx] = acc[i][j][r] + resid[idx] + bias[col];
            }
}

// ---------------- causal flash attention (r7 best: 53.0 us) ----------------
// grid (16 h, 16 j, 2 b), block 256 = 4 waves: sub=wave>>1 (32-q half of a
// 64-q strip), par=wave&1 (64-kv half of a 128-kv round). Strips j and 31-j
// -> exactly 17 rounds/block (uniform). XCD = h%8 (L2-pinned K/V).
// K [128kv][64d] + V^T [64d][128kv] LDS dbuf via global_load_lds w16
// (pre-swizzled source), 1 barrier/round. Parity merge via dead-K-LDS.
__global__ __launch_bounds__(256) void attn_fwd(
    const u16* __restrict__ Q, const u16* __restrict__ K,
    const u16* __restrict__ VT, u16* __restrict__ O)
{
    __shared__ __align__(16) unsigned char Kls[2 * 16384];  // [128 kv][64 d]
    __shared__ __align__(16) unsigned char Vls[2 * 16384];  // [64 d][128 kv]
    __shared__ __align__(16) unsigned char Ps[4 * 4096];    // per-wave P [32 q][64 kv]
    const int tid = threadIdx.x, lane = tid & 63, wave = tid >> 6;
    const int sub = wave >> 1, par = wave & 1;
    const int l15 = lane & 15, l4 = lane >> 4;
    const int h = blockIdx.x, jg = blockIdx.y, b = blockIdx.z;
    const size_t bbase = (size_t)b * NSEQ * E + h * HD;
    const u16* vt = VT + ((size_t)(b * 16 + h) * 64) * NSEQ;  // [d][n]

    unsigned char* Pw = Ps + wave * 4096;
    const int srowK = lane >> 3, kchunk = (lane & 7) ^ srowK;
    const int srowV = lane >> 4, vchunk = (lane & 15) ^ (((wave & 1) << 2) + srowV);

    auto stage = [&](int t, int buf) {
        const u16* Kg = K + bbase + (size_t)(t * 128) * E;
        const u16* vg = vt + t * 128;
        unsigned char* kd = Kls + buf * 16384 + wave * 1024;
        unsigned char* vd = Vls + buf * 16384 + wave * 1024;
#pragma unroll
        for (int i = 0; i < 4; ++i)
            GLOAD_LDS16(Kg + (size_t)(wave * 8 + i * 32 + srowK) * E + kchunk * 8, kd + i * 4096);
#pragma unroll
        for (int i = 0; i < 4; ++i)
            GLOAD_LDS16(vg + (size_t)(wave * 4 + i * 16 + srowV) * NSEQ + vchunk * 8, vd + i * 4096);
    };

    auto run_strip = [&](int jj) {
        const int qw0 = jj * 64 + sub * 32;
        const int R = (jj >> 1) + 1;

        short8 aq[2][2];
#pragma unroll
        for (int qt = 0; qt < 2; ++qt)
#pragma unroll
            for (int ks = 0; ks < 2; ++ks)
                aq[qt][ks] = *(const short8*)(Q + bbase + (size_t)(qw0 + qt * 16 + l15) * E + ks * 32 + l4 * 8);

        f32x4 accO[2][4] = {};
        float mrow[2] = {-5e29f, -5e29f};
        float lrow[2] = {0.f, 0.f};

        stage(0, 0);
        __syncthreads();

        auto step = [&](int t, auto mc) {
            constexpr bool MASK = decltype(mc)::v;
            const int buf = t & 1;
            if (t + 1 < R) stage(t + 1, buf ^ 1);
            const unsigned char* Kc = Kls + buf * 16384;
            const unsigned char* Vc = Vls + buf * 16384;

            f32x4 s[2][4] = {};
#pragma unroll
            for (int kvt = 0; kvt < 4; ++kvt) {
                const int kr = par * 64 + kvt * 16 + l15;
#pragma unroll
                for (int ks = 0; ks < 2; ++ks) {
                    short8 kfr = *(const short8*)(Kc + kr * 128 + ((ks * 64 + l4 * 16) ^ ((kr & 7) << 4)));
                    s[0][kvt] = mfma16(kfr, aq[0][ks], s[0][kvt]);
                    s[1][kvt] = mfma16(kfr, aq[1][ks], s[1][kvt]);
                }
            }

            if constexpr (MASK) {
#pragma unroll
                for (int qt = 0; qt < 2; ++qt) {
                    const int qg = qw0 + qt * 16 + l15;
#pragma unroll
                    for (int kvt = 0; kvt < 4; ++kvt)
#pragma unroll
                        for (int r = 0; r < 4; ++r) {
                            int kvg = t * 128 + par * 64 + kvt * 16 + l4 * 4 + r;
                            if (kvg > qg) s[qt][kvt][r] = -1e30f;
                        }
                }
            }

#pragma unroll
            for (int qt = 0; qt < 2; ++qt) {
                float m0 = fmaxf(fmaxf(s[qt][0][0], s[qt][0][1]), fmaxf(s[qt][0][2], s[qt][0][3]));
                float m1 = fmaxf(fmaxf(s[qt][1][0], s[qt][1][1]), fmaxf(s[qt][1][2], s[qt][1][3]));
                float m2 = fmaxf(fmaxf(s[qt][2][0], s[qt][2][1]), fmaxf(s[qt][2][2], s[qt][2][3]));
                float m3 = fmaxf(fmaxf(s[qt][3][0], s[qt][3][1]), fmaxf(s[qt][3][2], s[qt][3][3]));
                float pm = fmaxf(fmaxf(m0, m1), fmaxf(m2, m3));
                if (__any(pm > mrow[qt] + 8.f)) {
                    pm = fmaxf(pm, __shfl_xor(pm, 16));
                    pm = fmaxf(pm, __shfl_xor(pm, 32));
                    const float mn = fmaxf(mrow[qt], pm);
                    const float sc = exp2f(mrow[qt] - mn);
                    mrow[qt] = mn;
                    lrow[qt] *= sc;
#pragma unroll
                    for (int r = 0; r < 4; ++r) {
                        float scv = __shfl(sc, l4 * 4 + r);
#pragma unroll
                        for (int dt = 0; dt < 4; ++dt) accO[qt][dt][r] *= scv;
                    }
                }
                const int pr = qt * 16 + l15;
                const int sw = (l15 & 7) << 4;
#pragma unroll
                for (int kvt = 0; kvt < 4; ++kvt) {
                    float p0 = exp2f(s[qt][kvt][0] - mrow[qt]);
                    float p1 = exp2f(s[qt][kvt][1] - mrow[qt]);
                    float p2 = exp2f(s[qt][kvt][2] - mrow[qt]);
                    float p3 = exp2f(s[qt][kvt][3] - mrow[qt]);
                    lrow[qt] += (p0 + p1) + (p2 + p3);
                    uint2 pk = make_uint2(cvt_pk_bf16(p0, p1), cvt_pk_bf16(p2, p3));
                    *(uint2*)(Pw + pr * 128 + ((kvt * 32 + l4 * 8) ^ sw)) = pk;
                }
            }

#pragma unroll
            for (int ks2 = 0; ks2 < 2; ++ks2) {
                const int cb = ks2 * 64 + l4 * 16;
                short8 pf0 = *(const short8*)(Pw + l15 * 128 + (cb ^ ((l15 & 7) << 4)));
                short8 pf1 = *(const short8*)(Pw + (16 + l15) * 128 + (cb ^ ((l15 & 7) << 4)));
#pragma unroll
                for (int dt = 0; dt < 4; ++dt) {
                    const int vr = dt * 16 + l15;
                    short8 vfr = *(const short8*)(Vc + vr * 256 + ((par * 128 + cb) ^ ((vr & 7) << 4)));
                    accO[0][dt] = mfma16(pf0, vfr, accO[0][dt]);
                    accO[1][dt] = mfma16(pf1, vfr, accO[1][dt]);
                }
            }
            __syncthreads();
        };

        for (int t = 0; t + 1 < R; ++t) step(t, BC<false>{});
        step(R - 1, BC<true>{});

        f32x4* Mg = (f32x4*)Kls;
        if (par == 1) {
            f32x4 hd;
            hd[0] = mrow[0]; hd[1] = mrow[1]; hd[2] = lrow[0]; hd[3] = lrow[1];
            Mg[(sub * 9) * 64 + lane] = hd;
#pragma unroll
            for (int qt = 0; qt < 2; ++qt)
#pragma unroll
                for (int dt = 0; dt < 4; ++dt)
                    Mg[(sub * 9 + 1 + qt * 4 + dt) * 64 + lane] = accO[qt][dt];
        }
        __syncthreads();
        if (par == 0) {
            f32x4 hd = Mg[(sub * 9) * 64 + lane];
            float scA[2], scB[2];
#pragma unroll
            for (int qt = 0; qt < 2; ++qt) {
                const float mB = hd[qt], lB = hd[2 + qt];
                const float ms = fmaxf(mrow[qt], mB);
                scA[qt] = exp2f(mrow[qt] - ms);
                scB[qt] = exp2f(mB - ms);
                lrow[qt] = lrow[qt] * scA[qt] + lB * scB[qt];
            }
#pragma unroll
            for (int qt = 0; qt < 2; ++qt)
#pragma unroll
                for (int r = 0; r < 4; ++r) {
                    float sa = __shfl(scA[qt], l4 * 4 + r);
                    float sb = __shfl(scB[qt], l4 * 4 + r);
#pragma unroll
                    for (int dt = 0; dt < 4; ++dt) {
                        f32x4 ob = Mg[(sub * 9 + 1 + qt * 4 + dt) * 64 + lane];
                        accO[qt][dt][r] = accO[qt][dt][r] * sa + ob[r] * sb;
                    }
                }
            float linv[2];
#pragma unroll
            for (int qt = 0; qt < 2; ++qt) {
                float tl2 = lrow[qt];
                tl2 += __shfl_xor(tl2, 16);
                tl2 += __shfl_xor(tl2, 32);
                linv[qt] = 1.f / tl2;
            }
#pragma unroll
            for (int rt = 0; rt < 2; ++rt)
#pragma unroll
                for (int r = 0; r < 4; ++r) {
                    float lq = __shfl(linv[rt], l4 * 4 + r);
                    const int qg = qw0 + rt * 16 + l4 * 4 + r;
#pragma unroll
                    for (int dt = 0; dt < 4; ++dt)
                        O[bbase + (size_t)qg * E + dt * 16 + l15] = f2bf(accO[rt][dt][r] * lq);
                }
        }
        __syncthreads();  // protect scratch before next strip's stage(0,0)
    };

    run_strip(jg);
    run_strip(31 - jg);
}

extern "C" void kernel_launch(void* const* d_in, const int* in_sizes, int n_in,
                              void* d_out, int out_size, void* d_ws, size_t ws_size,
                              hipStream_t stream)
{
    const float* x    = (const float*)d_in[0];
    const float* ln_w = (const float*)d_in[1];
    const float* ln_b = (const float*)d_in[2];
    const float* Wq   = (const float*)d_in[3];
    const float* Wk   = (const float*)d_in[4];
    const float* Wv   = (const float*)d_in[5];
    const float* Wo   = (const float*)d_in[6];
    const float* bo   = (const float*)d_in[7];
    float* out = (float*)d_out;

    u16* ws  = (u16*)d_ws;
    u16* Wbf = ws;                                  // 4 * 2^20 bf16
    u16* xn  = Wbf + (size_t)4 * 1024 * 1024;       // 4096*1024 (reused as VT)
    u16* Qb  = xn + (size_t)4096 * 1024;
    u16* Kb  = Qb + (size_t)4096 * 1024;
    u16* Vb  = Kb + (size_t)4096 * 1024;
    u16* Ob  = Vb + (size_t)4096 * 1024;
    u16* VT  = xn;  // alias: xn dead after gemm0; VT = [32 bh][64 d][2048 n]

    prep_k<<<dim3(8192), dim3(256), 0, stream>>>(Wq, Wk, Wv, Wo, x, ln_w, ln_b, Wbf, xn);
    gemm_nt0<<<dim3(8, 32, 3), dim3(256), 0, stream>>>(xn, Wbf, Qb);
    vtrans<<<dim3(32, 32), dim3(256), 0, stream>>>(Vb, VT);
    attn_fwd<<<dim3(16, 16, 2), dim3(256), 0, stream>>>(Qb, Kb, VT, Ob);
    gemm_nt1<<<dim3(8, 64), dim3(256), 0, stream>>>(
        Ob, Wbf + (size_t)3 * 1024 * 1024, out, x, bo);
}

// Round 17
// 115.795 us; speedup vs baseline: 1.1237x; 1.0012x over previous
//
#include <hip/hip_runtime.h>

#define E 1024
#define NSEQ 2048
#define HEADS 16
#define HD 64

typedef unsigned short u16;
typedef short short8 __attribute__((ext_vector_type(8)));
typedef float f32x4 __attribute__((ext_vector_type(4)));

template<bool B> struct BC { static constexpr bool v = B; };

#define GLOAD_LDS16(gp, lp)                                        \
    __builtin_amdgcn_global_load_lds(                              \
        (const __attribute__((address_space(1))) void*)(gp),       \
        (__attribute__((address_space(3))) void*)(lp), 16, 0, 0)

__device__ __forceinline__ u16 f2bf(float f) {
    union { float f; unsigned u; } v; v.f = f;
    unsigned r = v.u + 0x7fffu + ((v.u >> 16) & 1u);
    return (u16)(r >> 16);
}

__device__ __forceinline__ unsigned cvt_pk_bf16(float lo, float hi) {
    unsigned r;
    asm("v_cvt_pk_bf16_f32 %0, %1, %2" : "=v"(r) : "v"(lo), "v"(hi));
    return r;
}

__device__ __forceinline__ f32x4 mfma16(short8 a, short8 b, f32x4 c) {
    return __builtin_amdgcn_mfma_f32_16x16x32_bf16(a, b, c, 0, 0, 0);
}

// ---------------- fused: weight f32->bf16 convert + LayerNorm ----------------
__global__ __launch_bounds__(256) void prep_k(
    const float* __restrict__ Wq, const float* __restrict__ Wk,
    const float* __restrict__ Wv, const float* __restrict__ Wo,
    const float* __restrict__ X, const float* __restrict__ w,
    const float* __restrict__ bb, u16* __restrict__ Wbf, u16* __restrict__ xn)
{
    if (blockIdx.x < 4096) {
        const unsigned i = (blockIdx.x * 256u + threadIdx.x) * 4u;
        const unsigned m = i >> 20;
        const float* src = (m == 0) ? Wq : (m == 1) ? Wk : (m == 2) ? Wv : Wo;
        const float4 v = *(const float4*)(src + (i & 0xFFFFFu));
        *(uint2*)(Wbf + i) = make_uint2(
            ((unsigned)f2bf(v.x)) | (((unsigned)f2bf(v.y)) << 16),
            ((unsigned)f2bf(v.z)) | (((unsigned)f2bf(v.w)) << 16));
        return;
    }
    const int row = blockIdx.x - 4096, tid = threadIdx.x;
    const int lane = tid & 63, wave = tid >> 6;
    const float4 v = ((const float4*)(X + (size_t)row * E))[tid];
    float s = v.x + v.y + v.z + v.w;
    float s2 = v.x * v.x + v.y * v.y + v.z * v.z + v.w * v.w;
#pragma unroll
    for (int off = 1; off < 64; off <<= 1) {
        s += __shfl_xor(s, off);
        s2 += __shfl_xor(s2, off);
    }
    __shared__ float red[8];
    if (lane == 0) { red[wave] = s; red[4 + wave] = s2; }
    __syncthreads();
    s = red[0] + red[1] + red[2] + red[3];
    s2 = red[4] + red[5] + red[6] + red[7];
    const float mu = s * (1.f / 1024.f);
    float var = s2 * (1.f / 1024.f) - mu * mu;
    var = fmaxf(var, 0.f);
    const float rs = rsqrtf(var + 1e-5f);
    const float4 wv = ((const float4*)w)[tid];
    const float4 bv = ((const float4*)bb)[tid];
    u16 o0 = f2bf((v.x - mu) * rs * wv.x + bv.x);
    u16 o1 = f2bf((v.y - mu) * rs * wv.y + bv.y);
    u16 o2 = f2bf((v.z - mu) * rs * wv.z + bv.z);
    u16 o3 = f2bf((v.w - mu) * rs * wv.w + bv.w);
    *(uint2*)(xn + (size_t)row * E + tid * 4) =
        make_uint2(((unsigned)o0) | (((unsigned)o1) << 16),
                   ((unsigned)o2) | (((unsigned)o3) << 16));
}

// ---------------- V transpose: V[b][n][h*64+d] -> VT[(b*16+h)][d][n] ----------------
__global__ __launch_bounds__(256) void vtrans(
    const u16* __restrict__ Vb, u16* __restrict__ VT)
{
    __shared__ u16 tl[64][65];
    const int t = threadIdx.x;
    const int ntile = blockIdx.x, bh = blockIdx.y;
    const int b = bh >> 4, h = bh & 15;
    const int n0 = ntile * 64;
    {
        const int nl = t >> 2;
        const u16* src = Vb + ((size_t)b * NSEQ + n0 + nl) * E + h * 64;
#pragma unroll
        for (int u = 0; u < 2; ++u) {
            const int d0 = (t & 3) * 16 + u * 8;
            short8 v = *(const short8*)(src + d0);
#pragma unroll
            for (int j = 0; j < 8; ++j) tl[nl][d0 + j] = (u16)v[j];
        }
    }
    __syncthreads();
    {
        const int d = t >> 2, nc = (t & 3) * 16;
        u16* dst = VT + ((size_t)bh * 64 + d) * NSEQ + n0 + nc;
#pragma unroll
        for (int u = 0; u < 2; ++u) {
            short8 o;
#pragma unroll
            for (int j = 0; j < 8; ++j) o[j] = (short)tl[nc + u * 8 + j][d];
            *(short8*)(dst + u * 8) = o;
        }
    }
}

// ---------------- NT GEMM (QKV): C[4096,1024] = A * W_z^T, 128x128 tile ----------------
__global__ __launch_bounds__(256) void gemm_nt0(
    const u16* __restrict__ A, const u16* __restrict__ Wbase,
    u16* __restrict__ outb)
{
    __shared__ __align__(16) unsigned char As[128 * 128];
    __shared__ __align__(16) unsigned char Bs[128 * 128];
    const int tid = threadIdx.x;
    const int lane = tid & 63, wave = tid >> 6;
    const int l15 = lane & 15, l4 = lane >> 4;
    const int wm = wave >> 1, wn = wave & 1;
    const int nt = blockIdx.x, mt = blockIdx.y, z = blockIdx.z;
    const u16* Bw = Wbase + (size_t)z * (E * (size_t)E);

    const int lrow8 = lane >> 3;
    const int lchunk = (lane & 7) ^ lrow8;
    const u16* gA = A + (size_t)(mt * 128 + lrow8) * E + lchunk * 8;
    const u16* gB = Bw + (size_t)(nt * 128 + lrow8) * E + lchunk * 8;

    f32x4 acc[4][4] = {};

    for (int kt = 0; kt < 16; ++kt) {
#pragma unroll
        for (int i = 0; i < 4; ++i) {
            const int rb = (i * 4 + wave) * 8;
            GLOAD_LDS16(gA + (size_t)rb * E + kt * 64, As + rb * 128);
            GLOAD_LDS16(gB + (size_t)rb * E + kt * 64, Bs + rb * 128);
        }
        __syncthreads();
#pragma unroll
        for (int ks = 0; ks < 2; ++ks) {
            short8 af[4], bfr[4];
#pragma unroll
            for (int i = 0; i < 4; ++i) {
                int ra = wm * 64 + i * 16 + l15;
                af[i] = *(const short8*)(As + ra * 128 + ((ks * 64 + l4 * 16) ^ ((ra & 7) << 4)));
                int rb2 = wn * 64 + i * 16 + l15;
                bfr[i] = *(const short8*)(Bs + rb2 * 128 + ((ks * 64 + l4 * 16) ^ ((rb2 & 7) << 4)));
            }
#pragma unroll
            for (int i = 0; i < 4; ++i)
#pragma unroll
                for (int j = 0; j < 4; ++j)
                    acc[i][j] = mfma16(af[i], bfr[j], acc[i][j]);
        }
        __syncthreads();
    }

    const int orow0 = mt * 128 + wm * 64, ocol0 = nt * 128 + wn * 64;
    u16* outz = outb + (size_t)z * (4096 * (size_t)E);
    const float osc = (z == 0) ? 0.18033688f : 1.0f;  // 0.125 * log2(e)
#pragma unroll
    for (int i = 0; i < 4; ++i)
#pragma unroll
        for (int j = 0; j < 4; ++j)
#pragma unroll
            for (int r = 0; r < 4; ++r) {
                int row = orow0 + i * 16 + l4 * 4 + r;
                int col = ocol0 + j * 16 + l15;
                outz[(size_t)row * E + col] = f2bf(acc[i][j][r] * osc);
            }
}

// ---------------- output projection: 64x128 tile, grid (8,64) = 2 blocks/CU ----------------
__global__ __launch_bounds__(256) void gemm_nt1(
    const u16* __restrict__ A, const u16* __restrict__ Bw,
    float* __restrict__ outf, const float* __restrict__ resid,
    const float* __restrict__ bias)
{
    __shared__ __align__(16) unsigned char As[64 * 128];    // 64 rows x 64 bf16
    __shared__ __align__(16) unsigned char Bs[128 * 128];   // 128 cols x 64 bf16
    const int tid = threadIdx.x;
    const int lane = tid & 63, wave = tid >> 6;
    const int l15 = lane & 15, l4 = lane >> 4;
    const int nt = blockIdx.x, mt = blockIdx.y;

    const int lrow8 = lane >> 3;
    const int lchunk = (lane & 7) ^ lrow8;
    const u16* gA = A + (size_t)(mt * 64 + lrow8) * E + lchunk * 8;
    const u16* gB = Bw + (size_t)(nt * 128 + lrow8) * E + lchunk * 8;

    f32x4 acc[4][2] = {};

    for (int kt = 0; kt < 16; ++kt) {
#pragma unroll
        for (int i = 0; i < 2; ++i) {    // A: rows wave*8 + i*32 (+0..7)
            const int rb = (i * 4 + wave) * 8;
            GLOAD_LDS16(gA + (size_t)rb * E + kt * 64, As + rb * 128);
        }
#pragma unroll
        for (int i = 0; i < 4; ++i) {    // B: rows wave*8 + i*32 (+0..7)
            const int rb = (i * 4 + wave) * 8;
            GLOAD_LDS16(gB + (size_t)rb * E + kt * 64, Bs + rb * 128);
        }
        __syncthreads();
#pragma unroll
        for (int ks = 0; ks < 2; ++ks) {
            short8 af[4], bfr[2];
#pragma unroll
            for (int i = 0; i < 4; ++i) {
                int ra = i * 16 + l15;
                af[i] = *(const short8*)(As + ra * 128 + ((ks * 64 + l4 * 16) ^ ((ra & 7) << 4)));
            }
#pragma unroll
            for (int j = 0; j < 2; ++j) {
                int rb2 = wave * 32 + j * 16 + l15;
                bfr[j] = *(const short8*)(Bs + rb2 * 128 + ((ks * 64 + l4 * 16) ^ ((rb2 & 7) << 4)));
            }
#pragma unroll
            for (int i = 0; i < 4; ++i)
#pragma unroll
                for (int j = 0; j < 2; ++j)
                    acc[i][j] = mfma16(af[i], bfr[j], acc[i][j]);
        }
        __syncthreads();
    }

    const int orow0 = mt * 64, ocol0 = nt * 128 + wave * 32;
#pragma unroll
    for (int i = 0; i < 4; ++i)
#pragma unroll
        for (int j = 0; j < 2; ++j)
#pragma unroll
            for (int r = 0; r < 4; ++r) {
                int row = orow0 + i * 16 + l4 * 4 + r;
                int col = ocol0 + j * 16 + l15;
                size_t idx = (size_t)row * E + col;
                outf[idx] = acc[i][j][r] + resid[idx] + bias[col];
            }
}

// ---------------- causal flash attention (r7 best: 53.0 us, FROZEN) ----------------
__global__ __launch_bounds__(256) void attn_fwd(
    const u16* __restrict__ Q, const u16* __restrict__ K,
    const u16* __restrict__ VT, u16* __restrict__ O)
{
    __shared__ __align__(16) unsigned char Kls[2 * 16384];  // [128 kv][64 d]
    __shared__ __align__(16) unsigned char Vls[2 * 16384];  // [64 d][128 kv]
    __shared__ __align__(16) unsigned char Ps[4 * 4096];    // per-wave P [32 q][64 kv]
    const int tid = threadIdx.x, lane = tid & 63, wave = tid >> 6;
    const int sub = wave >> 1, par = wave & 1;
    const int l15 = lane & 15, l4 = lane >> 4;
    const int h = blockIdx.x, jg = blockIdx.y, b = blockIdx.z;
    const size_t bbase = (size_t)b * NSEQ * E + h * HD;
    const u16* vt = VT + ((size_t)(b * 16 + h) * 64) * NSEQ;  // [d][n]

    unsigned char* Pw = Ps + wave * 4096;
    const int srowK = lane >> 3, kchunk = (lane & 7) ^ srowK;
    const int srowV = lane >> 4, vchunk = (lane & 15) ^ (((wave & 1) << 2) + srowV);

    auto stage = [&](int t, int buf) {
        const u16* Kg = K + bbase + (size_t)(t * 128) * E;
        const u16* vg = vt + t * 128;
        unsigned char* kd = Kls + buf * 16384 + wave * 1024;
        unsigned char* vd = Vls + buf * 16384 + wave * 1024;
#pragma unroll
        for (int i = 0; i < 4; ++i)
            GLOAD_LDS16(Kg + (size_t)(wave * 8 + i * 32 + srowK) * E + kchunk * 8, kd + i * 4096);
#pragma unroll
        for (int i = 0; i < 4; ++i)
            GLOAD_LDS16(vg + (size_t)(wave * 4 + i * 16 + srowV) * NSEQ + vchunk * 8, vd + i * 4096);
    };

    auto run_strip = [&](int jj) {
        const int qw0 = jj * 64 + sub * 32;
        const int R = (jj >> 1) + 1;

        short8 aq[2][2];
#pragma unroll
        for (int qt = 0; qt < 2; ++qt)
#pragma unroll
            for (int ks = 0; ks < 2; ++ks)
                aq[qt][ks] = *(const short8*)(Q + bbase + (size_t)(qw0 + qt * 16 + l15) * E + ks * 32 + l4 * 8);

        f32x4 accO[2][4] = {};
        float mrow[2] = {-5e29f, -5e29f};
        float lrow[2] = {0.f, 0.f};

        stage(0, 0);
        __syncthreads();

        auto step = [&](int t, auto mc) {
            constexpr bool MASK = decltype(mc)::v;
            const int buf = t & 1;
            if (t + 1 < R) stage(t + 1, buf ^ 1);
            const unsigned char* Kc = Kls + buf * 16384;
            const unsigned char* Vc = Vls + buf * 16384;

            f32x4 s[2][4] = {};
#pragma unroll
            for (int kvt = 0; kvt < 4; ++kvt) {
                const int kr = par * 64 + kvt * 16 + l15;
#pragma unroll
                for (int ks = 0; ks < 2; ++ks) {
                    short8 kfr = *(const short8*)(Kc + kr * 128 + ((ks * 64 + l4 * 16) ^ ((kr & 7) << 4)));
                    s[0][kvt] = mfma16(kfr, aq[0][ks], s[0][kvt]);
                    s[1][kvt] = mfma16(kfr, aq[1][ks], s[1][kvt]);
                }
            }

            if constexpr (MASK) {
#pragma unroll
                for (int qt = 0; qt < 2; ++qt) {
                    const int qg = qw0 + qt * 16 + l15;
#pragma unroll
                    for (int kvt = 0; kvt < 4; ++kvt)
#pragma unroll
                        for (int r = 0; r < 4; ++r) {
                            int kvg = t * 128 + par * 64 + kvt * 16 + l4 * 4 + r;
                            if (kvg > qg) s[qt][kvt][r] = -1e30f;
                        }
                }
            }

#pragma unroll
            for (int qt = 0; qt < 2; ++qt) {
                float m0 = fmaxf(fmaxf(s[qt][0][0], s[qt][0][1]), fmaxf(s[qt][0][2], s[qt][0][3]));
                float m1 = fmaxf(fmaxf(s[qt][1][0], s[qt][1][1]), fmaxf(s[qt][1][2], s[qt][1][3]));
                float m2 = fmaxf(fmaxf(s[qt][2][0], s[qt][2][1]), fmaxf(s[qt][2][2], s[qt][2][3]));
                float m3 = fmaxf(fmaxf(s[qt][3][0], s[qt][3][1]), fmaxf(s[qt][3][2], s[qt][3][3]));
                float pm = fmaxf(fmaxf(m0, m1), fmaxf(m2, m3));
                if (__any(pm > mrow[qt] + 8.f)) {
                    pm = fmaxf(pm, __shfl_xor(pm, 16));
                    pm = fmaxf(pm, __shfl_xor(pm, 32));
                    const float mn = fmaxf(mrow[qt], pm);
                    const float sc = exp2f(mrow[qt] - mn);
                    mrow[qt] = mn;
                    lrow[qt] *= sc;
#pragma unroll
                    for (int r = 0; r < 4; ++r) {
                        float scv = __shfl(sc, l4 * 4 + r);
#pragma unroll
                        for (int dt = 0; dt < 4; ++dt) accO[qt][dt][r] *= scv;
                    }
                }
                const int pr = qt * 16 + l15;
                const int sw = (l15 & 7) << 4;
#pragma unroll
                for (int kvt = 0; kvt < 4; ++kvt) {
                    float p0 = exp2f(s[qt][kvt][0] - mrow[qt]);
                    float p1 = exp2f(s[qt][kvt][1] - mrow[qt]);
                    float p2 = exp2f(s[qt][kvt][2] - mrow[qt]);
                    float p3 = exp2f(s[qt][kvt][3] - mrow[qt]);
                    lrow[qt] += (p0 + p1) + (p2 + p3);
                    uint2 pk = make_uint2(cvt_pk_bf16(p0, p1), cvt_pk_bf16(p2, p3));
                    *(uint2*)(Pw + pr * 128 + ((kvt * 32 + l4 * 8) ^ sw)) = pk;
                }
            }

#pragma unroll
            for (int ks2 = 0; ks2 < 2; ++ks2) {
                const int cb = ks2 * 64 + l4 * 16;
                short8 pf0 = *(const short8*)(Pw + l15 * 128 + (cb ^ ((l15 & 7) << 4)));
                short8 pf1 = *(const short8*)(Pw + (16 + l15) * 128 + (cb ^ ((l15 & 7) << 4)));
#pragma unroll
                for (int dt = 0; dt < 4; ++dt) {
                    const int vr = dt * 16 + l15;
                    short8 vfr = *(const short8*)(Vc + vr * 256 + ((par * 128 + cb) ^ ((vr & 7) << 4)));
                    accO[0][dt] = mfma16(pf0, vfr, accO[0][dt]);
                    accO[1][dt] = mfma16(pf1, vfr, accO[1][dt]);
                }
            }
            __syncthreads();
        };

        for (int t = 0; t + 1 < R; ++t) step(t, BC<false>{});
        step(R - 1, BC<true>{});

        f32x4* Mg = (f32x4*)Kls;
        if (par == 1) {
            f32x4 hd;
            hd[0] = mrow[0]; hd[1] = mrow[1]; hd[2] = lrow[0]; hd[3] = lrow[1];
            Mg[(sub * 9) * 64 + lane] = hd;
#pragma unroll
            for (int qt = 0; qt < 2; ++qt)
#pragma unroll
                for (int dt = 0; dt < 4; ++dt)
                    Mg[(sub * 9 + 1 + qt * 4 + dt) * 64 + lane] = accO[qt][dt];
        }
        __syncthreads();
        if (par == 0) {
            f32x4 hd = Mg[(sub * 9) * 64 + lane];
            float scA[2], scB[2];
#pragma unroll
            for (int qt = 0; qt < 2; ++qt) {
                const float mB = hd[qt], lB = hd[2 + qt];
                const float ms = fmaxf(mrow[qt], mB);
                scA[qt] = exp2f(mrow[qt] - ms);
                scB[qt] = exp2f(mB - ms);
                lrow[qt] = lrow[qt] * scA[qt] + lB * scB[qt];
            }
#pragma unroll
            for (int qt = 0; qt < 2; ++qt)
#pragma unroll
                for (int r = 0; r < 4; ++r) {
                    float sa = __shfl(scA[qt], l4 * 4 + r);
                    float sb = __shfl(scB[qt], l4 * 4 + r);
#pragma unroll
                    for (int dt = 0; dt < 4; ++dt) {
                        f32x4 ob = Mg[(sub * 9 + 1 + qt * 4 + dt) * 64 + lane];
                        accO[qt][dt][r] = accO[qt][dt][r] * sa + ob[r] * sb;
                    }
                }
            float linv[2];
#pragma unroll
            for (int qt = 0; qt < 2; ++qt) {
                float tl2 = lrow[qt];
                tl2 += __shfl_xor(tl2, 16);
                tl2 += __shfl_xor(tl2, 32);
                linv[qt] = 1.f / tl2;
            }
#pragma unroll
            for (int rt = 0; rt < 2; ++rt)
#pragma unroll
                for (int r = 0; r < 4; ++r) {
                    float lq = __shfl(linv[rt], l4 * 4 + r);
                    const int qg = qw0 + rt * 16 + l4 * 4 + r;
#pragma unroll
                    for (int dt = 0; dt < 4; ++dt)
                        O[bbase + (size_t)qg * E + dt * 16 + l15] = f2bf(accO[rt][dt][r] * lq);
                }
        }
        __syncthreads();  // protect scratch before next strip's stage(0,0)
    };

    run_strip(jg);
    run_strip(31 - jg);
}

extern "C" void kernel_launch(void* const* d_in, const int* in_sizes, int n_in,
                              void* d_out, int out_size, void* d_ws, size_t ws_size,
                              hipStream_t stream)
{
    const float* x    = (const float*)d_in[0];
    const float* ln_w = (const float*)d_in[1];
    const float* ln_b = (const float*)d_in[2];
    const float* Wq   = (const float*)d_in[3];
    const float* Wk   = (const float*)d_in[4];
    const float* Wv   = (const float*)d_in[5];
    const float* Wo   = (const float*)d_in[6];
    const float* bo   = (const float*)d_in[7];
    float* out = (float*)d_out;

    u16* ws  = (u16*)d_ws;
    u16* Wbf = ws;                                  // 4 * 2^20 bf16
    u16* xn  = Wbf + (size_t)4 * 1024 * 1024;       // 4096*1024 (reused as VT)
    u16* Qb  = xn + (size_t)4096 * 1024;
    u16* Kb  = Qb + (size_t)4096 * 1024;
    u16* Vb  = Kb + (size_t)4096 * 1024;
    u16* Ob  = Vb + (size_t)4096 * 1024;
    u16* VT  = xn;  // alias: xn dead after gemm0; VT = [32 bh][64 d][2048 n]

    prep_k<<<dim3(8192), dim3(256), 0, stream>>>(Wq, Wk, Wv, Wo, x, ln_w, ln_b, Wbf, xn);
    gemm_nt0<<<dim3(8, 32, 3), dim3(256), 0, stream>>>(xn, Wbf, Qb);
    vtrans<<<dim3(32, 32), dim3(256), 0, stream>>>(Vb, VT);
    attn_fwd<<<dim3(16, 16, 2), dim3(256), 0, stream>>>(Qb, Kb, VT, Ob);
    gemm_nt1<<<dim3(8, 64), dim3(256), 0, stream>>>(
        Ob, Wbf + (size_t)3 * 1024 * 1024, out, x, bo);
}